// Round 1
// baseline (9989.233 us; speedup 1.0000x reference)
//
#include <hip/hip_runtime.h>
#include <hip/hip_bf16.h>
#include <math.h>

#define HW 16384
#define IMH 128
#define IMW 128

// ---------------- logits = fd_w @ x + fd_b ----------------
__global__ __launch_bounds__(256) void k_logits(const float* __restrict__ x,
                                                const float* __restrict__ fd_w,
                                                const float* __restrict__ fd_b,
                                                float* __restrict__ probs) {
  __shared__ float w[256 * 32];
  int b = blockIdx.y;
  int pix = blockIdx.x * 256 + threadIdx.x;
  float acc[32];
#pragma unroll
  for (int k = 0; k < 32; k++) acc[k] = fd_b[k];
  const float* xp = x + (size_t)b * 512 * HW + pix;
  for (int half = 0; half < 2; half++) {
    int cbase = half * 256;
    __syncthreads();
    for (int i = threadIdx.x; i < 256 * 32; i += 256) {
      int c = i >> 5, k = i & 31;
      w[i] = fd_w[k * 512 + cbase + c];
    }
    __syncthreads();
    for (int c = 0; c < 256; c++) {
      float xv = xp[(size_t)(cbase + c) * HW];
#pragma unroll
      for (int k = 0; k < 32; k++) acc[k] += xv * w[c * 32 + k];
    }
  }
#pragma unroll
  for (int k = 0; k < 32; k++) probs[((size_t)(b * 32 + k)) * HW + pix] = acc[k];
}

// ---------------- softmax over spatial (16384) per (b,k) ----------------
__global__ __launch_bounds__(256) void k_softmax_sp(float* __restrict__ probs) {
  int row = blockIdx.x;
  float* p = probs + (size_t)row * HW;
  __shared__ float red[256];
  float mx = -1e30f;
  for (int i = threadIdx.x; i < HW; i += 256) mx = fmaxf(mx, p[i]);
  red[threadIdx.x] = mx;
  __syncthreads();
  for (int s = 128; s > 0; s >>= 1) {
    if (threadIdx.x < s) red[threadIdx.x] = fmaxf(red[threadIdx.x], red[threadIdx.x + s]);
    __syncthreads();
  }
  mx = red[0];
  __syncthreads();
  float sum = 0.f;
  for (int i = threadIdx.x; i < HW; i += 256) sum += expf(p[i] - mx);
  red[threadIdx.x] = sum;
  __syncthreads();
  for (int s = 128; s > 0; s >>= 1) {
    if (threadIdx.x < s) red[threadIdx.x] += red[threadIdx.x + s];
    __syncthreads();
  }
  float inv = 1.0f / red[0];
  for (int i = threadIdx.x; i < HW; i += 256) p[i] = expf(p[i] - mx) * inv;
}

// ---------------- pooled = leaky(mean 32x32 window) ----------------
__global__ __launch_bounds__(256) void k_pool(const float* __restrict__ x,
                                              float* __restrict__ pooled) {
  int b = blockIdx.z, ih = blockIdx.y, iw = blockIdx.x;
  for (int c = threadIdx.x; c < 512; c += 256) {
    const float* xp = x + ((size_t)(b * 512 + c) * IMH + ih * 32) * IMW + iw * 32;
    float s = 0.f;
    for (int r = 0; r < 32; r++)
      for (int cc = 0; cc < 32; cc++) s += xp[r * IMW + cc];
    s *= (1.0f / 1024.0f);
    if (s < 0.f) s *= 0.01f;
    pooled[(b * 512 + c) * 16 + ih * 4 + iw] = s;
  }
}

// ---------------- off / scl / ang heads ----------------
__global__ __launch_bounds__(256) void k_heads(const float* __restrict__ pooled,
                                               const float* __restrict__ off_w, const float* __restrict__ off_b,
                                               const float* __restrict__ scale_w, const float* __restrict__ scale_b,
                                               const float* __restrict__ angle_w, const float* __restrict__ angle_b,
                                               float* __restrict__ f_off, float* __restrict__ f_scl,
                                               float* __restrict__ f_ang) {
  int b = blockIdx.z, ih = blockIdx.y, iw = blockIdx.x;
  __shared__ float pl[512];
  int ij = ih * 4 + iw;
  for (int c = threadIdx.x; c < 512; c += 256) pl[c] = pooled[(b * 512 + c) * 16 + ij];
  __syncthreads();
  int t = threadIdx.x;
  if (t < 40) {
    const float* wt;
    float bias;
    if (t < 16) { wt = off_w + t * 512; bias = off_b[t]; }
    else if (t < 32) { int u = t - 16; wt = scale_w + u * 512; bias = scale_b[u]; }
    else { int u = t - 32; wt = angle_w + u * 512; bias = angle_b[u]; }
    float s = bias;
    for (int c = 0; c < 512; c++) s += pl[c] * wt[c];
    if (t < 16) {
      int n = t / 2, l = t % 2;
      f_off[((b * 8 + n) * 2 + l) * 16 + ij] = s * (1.0f / 32.0f);
    } else if (t < 32) {
      int u = t - 16;
      int n = u / 2, l = u % 2;
      f_scl[((b * 8 + n) * 2 + l) * 16 + ij] = s;
    } else {
      int n = t - 32;
      f_ang[(b * 8 + n) * 16 + ij] = s;
    }
  }
}

// ---------------- sampling grid ----------------
__global__ __launch_bounds__(256) void k_grid(const float* __restrict__ f_off,
                                              const float* __restrict__ f_scl,
                                              const float* __restrict__ f_ang,
                                              float* __restrict__ grid) {
  int p = blockIdx.y;
  int hw = blockIdx.x * 256 + threadIdx.x;
  int h = hw >> 7, w = hw & 127;
  int ih = h >> 5, r = h & 31, iw = w >> 5, cs = w & 31;
  int ij = ih * 4 + iw;
  float off0 = f_off[(p * 2 + 0) * 16 + ij], off1 = f_off[(p * 2 + 1) * 16 + ij];
  float scl0 = f_scl[(p * 2 + 0) * 16 + ij], scl1 = f_scl[(p * 2 + 1) * 16 + ij];
  float a = f_ang[p * 16 + ij];
  float sa = sinf(a), ca = cosf(a);
  float bwv = ((float)cs - 15.5f) * (2.0f / 127.0f);
  float bhv = ((float)r - 15.5f) * (2.0f / 127.0f);
  float wc0 = bwv * (scl0 + 1.0f);
  float wc1 = bhv * (scl1 + 1.0f);
  float wrw = -1.0f + 2.0f * ((float)(iw * 32) + 15.5f) / 127.0f;
  float wrh = -1.0f + 2.0f * ((float)(ih * 32) + 15.5f) / 127.0f;
  float c0 = wrw + (-wc1 * sa + wc0 * ca) + off0;
  float c1 = wrh + (wc1 * ca + wc0 * sa) + off1;
  size_t o = ((size_t)p * HW + hw) * 2;
  grid[o] = c0;
  grid[o + 1] = c1;
}

// ---------------- generic 512x512 1x1 conv: Y[b][m][n] = W[m][:]·X[b][:][n] + bias ----------------
__global__ __launch_bounds__(256) void k_gemm512(const float* __restrict__ X,
                                                 const float* __restrict__ Wt,
                                                 const float* __restrict__ bias,
                                                 float* __restrict__ Y) {
  __shared__ float lw[16][64];
  __shared__ float lx[16][64];
  int b = blockIdx.z;
  int m0 = blockIdx.y * 64;
  int n0 = blockIdx.x * 64;
  int tid = threadIdx.x;
  int tm = tid >> 4, tn = tid & 15;
  float acc[4][4] = {};
  const float* Xb = X + (size_t)b * 512 * HW;
  for (int c0 = 0; c0 < 512; c0 += 16) {
    {
      int m = tid >> 2, c4 = (tid & 3) * 4;
      const float* wp = Wt + (size_t)(m0 + m) * 512 + c0 + c4;
      float4 v = *reinterpret_cast<const float4*>(wp);
      lw[c4 + 0][m] = v.x;
      lw[c4 + 1][m] = v.y;
      lw[c4 + 2][m] = v.z;
      lw[c4 + 3][m] = v.w;
    }
    {
      int kk = tid >> 4, n4 = (tid & 15) * 4;
      const float* xp = Xb + (size_t)(c0 + kk) * HW + n0 + n4;
      *reinterpret_cast<float4*>(&lx[kk][n4]) = *reinterpret_cast<const float4*>(xp);
    }
    __syncthreads();
#pragma unroll
    for (int kk = 0; kk < 16; kk++) {
      float wv[4], xv[4];
      *reinterpret_cast<float4*>(wv) = *reinterpret_cast<const float4*>(&lw[kk][tm * 4]);
      *reinterpret_cast<float4*>(xv) = *reinterpret_cast<const float4*>(&lx[kk][tn * 4]);
#pragma unroll
      for (int i = 0; i < 4; i++)
#pragma unroll
        for (int j = 0; j < 4; j++) acc[i][j] += wv[i] * xv[j];
    }
    __syncthreads();
  }
#pragma unroll
  for (int i = 0; i < 4; i++) {
    int m = m0 + tm * 4 + i;
    float bv = bias[m];
    float4 vo = make_float4(acc[i][0] + bv, acc[i][1] + bv, acc[i][2] + bv, acc[i][3] + bv);
    *reinterpret_cast<float4*>(Y + ((size_t)b * 512 + m) * HW + n0 + tn * 4) = vo;
  }
}

// ---------------- bilinear grid-sample with zero padding ----------------
__global__ __launch_bounds__(256) void k_gsample(const float* __restrict__ img, int CH, int pmod,
                                                 const float* __restrict__ grid,
                                                 float* __restrict__ out) {
  int p = blockIdx.y;
  int hw = blockIdx.x * 256 + threadIdx.x;
  const float* ib = img + (size_t)(p % pmod) * CH * HW;
  float gx = grid[((size_t)p * HW + hw) * 2 + 0];
  float gy = grid[((size_t)p * HW + hw) * 2 + 1];
  gx = (gx + 1.0f) * 0.5f * 127.0f;
  gy = (gy + 1.0f) * 0.5f * 127.0f;
  float x0f = floorf(gx), y0f = floorf(gy);
  float wx1 = gx - x0f, wx0 = 1.0f - wx1;
  float wy1 = gy - y0f, wy0 = 1.0f - wy1;
  int x0 = (int)x0f, y0 = (int)y0f;
  bool vx0 = (x0f >= 0.f) && (x0f <= 127.f);
  bool vx1 = (x0f + 1.0f >= 0.f) && (x0f + 1.0f <= 127.f);
  bool vy0 = (y0f >= 0.f) && (y0f <= 127.f);
  bool vy1 = (y0f + 1.0f >= 0.f) && (y0f + 1.0f <= 127.f);
  int x0c = min(max(x0, 0), 127), x1c = min(max(x0 + 1, 0), 127);
  int y0c = min(max(y0, 0), 127), y1c = min(max(y0 + 1, 0), 127);
  float w00 = wx0 * wy0 * ((vx0 && vy0) ? 1.f : 0.f);
  float w01 = wx1 * wy0 * ((vx1 && vy0) ? 1.f : 0.f);
  float w10 = wx0 * wy1 * ((vx0 && vy1) ? 1.f : 0.f);
  float w11 = wx1 * wy1 * ((vx1 && vy1) ? 1.f : 0.f);
  int o00 = y0c * IMW + x0c, o01 = y0c * IMW + x1c;
  int o10 = y1c * IMW + x0c, o11 = y1c * IMW + x1c;
  for (int c = 0; c < CH; c++) {
    const float* ic = ib + (size_t)c * HW;
    float v = ic[o00] * w00 + ic[o01] * w01 + ic[o10] * w10 + ic[o11] * w11;
    out[((size_t)p * CH + c) * HW + hw] = v;
  }
}

// ---------------- lc[p*16+win][k][d] = sum_s tp[k][s]*tx[d][s] ----------------
__global__ __launch_bounds__(256) void k_lc(const float* __restrict__ tx,
                                            const float* __restrict__ tp,
                                            float* __restrict__ lc) {
  int idx2 = blockIdx.x;
  int p = idx2 >> 4, win = idx2 & 15;
  int ih = win >> 2, iw = win & 3;
  __shared__ float ltx[64][65];
  __shared__ float ltp[64][33];
  int tid = threadIdx.x;
  int k = tid >> 3, dg = tid & 7;
  float acc[8] = {};
  const float* txp = tx + (size_t)p * 64 * HW;
  const float* tpp = tp + (size_t)p * 32 * HW;
  int base = (ih * 32) * IMW + iw * 32;
  for (int s0 = 0; s0 < 1024; s0 += 64) {
#pragma unroll
    for (int i = 0; i < 16; i++) {
      int linear = tid + i * 256;
      int d = linear >> 6, sl = linear & 63;
      int s = s0 + sl;
      int pix = base + (s >> 5) * IMW + (s & 31);
      ltx[sl][d] = txp[(size_t)d * HW + pix];
    }
#pragma unroll
    for (int i = 0; i < 8; i++) {
      int linear = tid + i * 256;
      int kk = linear >> 6, sl = linear & 63;
      int s = s0 + sl;
      int pix = base + (s >> 5) * IMW + (s & 31);
      ltp[sl][kk] = tpp[(size_t)kk * HW + pix];
    }
    __syncthreads();
    for (int sl = 0; sl < 64; sl++) {
      float tv = ltp[sl][k];
#pragma unroll
      for (int j = 0; j < 8; j++) acc[j] += tv * ltx[sl][dg * 8 + j];
    }
    __syncthreads();
  }
  float* lp = lc + ((size_t)idx2 * 32 + k) * 64 + dg * 8;
#pragma unroll
  for (int j = 0; j < 8; j++) lp[j] = acc[j];
}

// ---------------- v2[j][k][o] = gc[j][k]·v_w[o] + v_b[o] ----------------
__global__ __launch_bounds__(256) void k_v2(const float* __restrict__ gc,
                                            const float* __restrict__ v_w,
                                            const float* __restrict__ v_b,
                                            float* __restrict__ v2) {
  int j = blockIdx.x >> 5, k = blockIdx.x & 31;
  __shared__ float g[512];
  for (int c = threadIdx.x; c < 512; c += 256) g[c] = gc[((size_t)j * 32 + k) * 512 + c];
  __syncthreads();
  for (int o = threadIdx.x; o < 512; o += 256) {
    float s = v_b[o];
    const float* wp = v_w + (size_t)o * 512;
    for (int c = 0; c < 512; c++) s += g[c] * wp[c];
    v2[((size_t)j * 32 + k) * 512 + o] = s;
  }
}

// ---------------- attention per (b, win, n) ----------------
__global__ __launch_bounds__(256) void k_attn(const float* __restrict__ Yq,
                                              const float* __restrict__ lc,
                                              const float* __restrict__ v2,
                                              float* __restrict__ att) {
  int n = blockIdx.x, win = blockIdx.y, b = blockIdx.z;
  int ih = win >> 2, iw = win & 3;
  __shared__ float llc[32 * 64];
  __shared__ float lv[32 * 64];
  int bnw = b * 16 + win;
  const float* lcp = lc + (size_t)(bnw * 8 + n) * 2048;
  const float* vp = v2 + (size_t)(bnw & 1) * 32 * 512 + n * 64;
  for (int i = threadIdx.x; i < 2048; i += 256) {
    llc[i] = lcp[i];
    int k = i >> 6, d = i & 63;
    lv[i] = vp[(size_t)k * 512 + d];
  }
  __syncthreads();
  const float scale = 0.125f;
  for (int rep = 0; rep < 4; rep++) {
    int s = threadIdx.x + rep * 256;
    int pix = (ih * 32 + (s >> 5)) * IMW + iw * 32 + (s & 31);
    const float* qp = Yq + ((size_t)(b * 512 + n * 64)) * HW + pix;
    float q[64];
#pragma unroll
    for (int d = 0; d < 64; d++) q[d] = qp[(size_t)d * HW];
    float dots[32];
#pragma unroll
    for (int k = 0; k < 32; k++) {
      float s2 = 0.f;
#pragma unroll
      for (int d = 0; d < 64; d++) s2 += q[d] * llc[k * 64 + d];
      dots[k] = s2 * scale;
    }
    float mx = -1e30f;
#pragma unroll
    for (int k = 0; k < 32; k++) mx = fmaxf(mx, dots[k]);
    float sum = 0.f;
#pragma unroll
    for (int k = 0; k < 32; k++) {
      dots[k] = expf(dots[k] - mx);
      sum += dots[k];
    }
    float inv = 1.0f / sum;
    float outv[64];
#pragma unroll
    for (int d = 0; d < 64; d++) outv[d] = 0.f;
#pragma unroll
    for (int k = 0; k < 32; k++) {
      float a = dots[k] * inv;
#pragma unroll
      for (int d = 0; d < 64; d++) outv[d] += a * lv[k * 64 + d];
    }
    float* op = att + ((size_t)(b * 512 + n * 64)) * HW + pix;
#pragma unroll
    for (int d = 0; d < 64; d++) op[(size_t)d * HW] = outv[d];
  }
}

// ---------------- 3x3 conv + BN + ReLU, dual-source input (concat) ----------------
#define KC 8
__global__ __launch_bounds__(256) void k_conv(const float* __restrict__ srcA, int CA,
                                              const float* __restrict__ srcB, int CB,
                                              const float* __restrict__ Wc,
                                              const float* __restrict__ bn_g, const float* __restrict__ bn_b,
                                              const float* __restrict__ bn_m, const float* __restrict__ bn_v,
                                              float* __restrict__ Y) {
  __shared__ float lx[KC][10][18];
  __shared__ float lw[KC * 9][64];
  int Cin = CA + CB;
  int b = blockIdx.z;
  int o0 = blockIdx.y * 64;
  int tile = blockIdx.x;
  int w0 = (tile & 7) * 16, h0 = (tile >> 3) * 8;
  int tid = threadIdx.x;
  int og = tid >> 5;
  int pg = tid & 31;
  int row = pg >> 2, wq = pg & 3;
  float acc[8][4] = {};
  for (int c0 = 0; c0 < Cin; c0 += KC) {
    for (int linear = tid; linear < KC * 10 * 18; linear += 256) {
      int c = linear / 180, rem = linear % 180;
      int rr = rem / 18, cc = rem % 18;
      int gh = h0 + rr - 1, gw = w0 + cc - 1;
      float v = 0.f;
      if (gh >= 0 && gh < IMH && gw >= 0 && gw < IMW) {
        int cg = c0 + c;
        const float* src = (cg < CA) ? (srcA + (size_t)(b * CA + cg) * HW)
                                     : (srcB + (size_t)(b * CB + cg - CA) * HW);
        v = src[gh * IMW + gw];
      }
      lx[c][rr][cc] = v;
    }
    for (int linear = tid; linear < KC * 9 * 64; linear += 256) {
      int o = linear / 72, rem = linear % 72;
      lw[rem][o] = Wc[((size_t)(o0 + o) * Cin + c0) * 9 + rem];
    }
    __syncthreads();
#pragma unroll
    for (int c = 0; c < KC; c++) {
#pragma unroll
      for (int ky = 0; ky < 3; ky++) {
#pragma unroll
        for (int kx = 0; kx < 3; kx++) {
          float xv[4];
#pragma unroll
          for (int j = 0; j < 4; j++) xv[j] = lx[c][row + ky][wq * 4 + j + kx];
          const float* wp = &lw[c * 9 + ky * 3 + kx][og * 8];
#pragma unroll
          for (int i = 0; i < 8; i++) {
            float wv = wp[i];
#pragma unroll
            for (int j = 0; j < 4; j++) acc[i][j] += wv * xv[j];
          }
        }
      }
    }
    __syncthreads();
  }
#pragma unroll
  for (int i = 0; i < 8; i++) {
    int o = o0 + og * 8 + i;
    float sc = bn_g[o] * rsqrtf(bn_v[o] + 1e-5f);
    float sh = bn_b[o] - bn_m[o] * sc;
    float* yp = Y + ((size_t)(b * 512 + o) * IMH + h0 + row) * IMW + w0 + wq * 4;
#pragma unroll
    for (int j = 0; j < 4; j++) {
      float v = acc[i][j] * sc + sh;
      yp[j] = fmaxf(v, 0.f);
    }
  }
}

extern "C" void kernel_launch(void* const* d_in, const int* in_sizes, int n_in,
                              void* d_out, int out_size, void* d_ws, size_t ws_size,
                              hipStream_t stream) {
  const float* x = (const float*)d_in[0];
  const float* gc = (const float*)d_in[1];
  const float* fd_w = (const float*)d_in[2];
  const float* fd_b = (const float*)d_in[3];
  const float* off_w = (const float*)d_in[4];
  const float* off_b = (const float*)d_in[5];
  const float* scale_w = (const float*)d_in[6];
  const float* scale_b = (const float*)d_in[7];
  const float* angle_w = (const float*)d_in[8];
  const float* angle_b = (const float*)d_in[9];
  const float* q_w = (const float*)d_in[10];
  const float* q_b = (const float*)d_in[11];
  const float* k_w = (const float*)d_in[12];
  const float* k_b = (const float*)d_in[13];
  const float* v_w = (const float*)d_in[14];
  const float* v_b = (const float*)d_in[15];
  const float* proj_w = (const float*)d_in[16];
  const float* proj_b = (const float*)d_in[17];
  const float* conv1_w = (const float*)d_in[18];
  const float* bn1_g = (const float*)d_in[19];
  const float* bn1_b = (const float*)d_in[20];
  const float* bn1_m = (const float*)d_in[21];
  const float* bn1_v = (const float*)d_in[22];
  const float* conv2_w = (const float*)d_in[23];
  const float* bn2_g = (const float*)d_in[24];
  const float* bn2_b = (const float*)d_in[25];
  const float* bn2_m = (const float*)d_in[26];
  const float* bn2_v = (const float*)d_in[27];

  float* ws = (float*)d_ws;
  float* f_probs = ws; ws += 1048576;          // (B,32,HW)
  float* f_grid = ws; ws += 524288;            // (16,HW,2)
  float* f_pooled = ws; ws += 16384;           // (B,512,16)
  float* f_off = ws; ws += 512;                // (16,2,16)
  float* f_scl = ws; ws += 512;
  float* f_ang = ws; ws += 256;
  float* f_lc = ws; ws += 524288;              // (256,32,64)
  float* f_v2 = ws; ws += 32768;               // (2,32,512)
  float* f_tp = ws; ws += 8388608;             // (16,32,HW)
  float* f_A = ws; ws += 16777216;             // Ykey -> h1
  float* f_B = ws; ws += 16777216;             // Yq
  float* f_C = ws; ws += 16777216;             // tx -> ctx
  float* f_att = (float*)d_out;                // attention output lives in d_out

  // 1. logits
  k_logits<<<dim3(64, 2), 256, 0, stream>>>(x, fd_w, fd_b, f_probs);
  // 2. spatial softmax
  k_softmax_sp<<<dim3(64), 256, 0, stream>>>(f_probs);
  // 3. pooled
  k_pool<<<dim3(4, 4, 2), 256, 0, stream>>>(x, f_pooled);
  // 4. heads
  k_heads<<<dim3(4, 4, 2), 256, 0, stream>>>(f_pooled, off_w, off_b, scale_w, scale_b,
                                             angle_w, angle_b, f_off, f_scl, f_ang);
  // 5. grid
  k_grid<<<dim3(64, 16), 256, 0, stream>>>(f_off, f_scl, f_ang, f_grid);
  // 6. key_feat = k_w @ x
  k_gemm512<<<dim3(256, 8, 2), 256, 0, stream>>>(x, k_w, k_b, f_A);
  // 7. Yq = q_w @ x
  k_gemm512<<<dim3(256, 8, 2), 256, 0, stream>>>(x, q_w, q_b, f_B);
  // 8. tx = gridsample(key_feat)
  k_gsample<<<dim3(64, 16), 256, 0, stream>>>(f_A, 64, 16, f_grid, f_C);
  // 9. tp = gridsample(tiled probs)
  k_gsample<<<dim3(64, 16), 256, 0, stream>>>(f_probs, 32, 2, f_grid, f_tp);
  // 10. lc
  k_lc<<<dim3(256), 256, 0, stream>>>(f_C, f_tp, f_lc);
  // 11. v2
  k_v2<<<dim3(64), 256, 0, stream>>>(gc, v_w, v_b, f_v2);
  // 12. attention -> att (d_out as scratch)
  k_attn<<<dim3(8, 16, 2), 256, 0, stream>>>(f_B, f_lc, f_v2, f_att);
  // 13. ctx = proj_w @ att
  k_gemm512<<<dim3(256, 8, 2), 256, 0, stream>>>(f_att, proj_w, proj_b, f_C);
  // 14. conv1 (concat(x, ctx)) + bn + relu -> h1 (f_A)
  k_conv<<<dim3(128, 8, 2), 256, 0, stream>>>(x, 512, f_C, 512, conv1_w,
                                              bn1_g, bn1_b, bn1_m, bn1_v, f_A);
  // 15. conv2 + bn + relu -> d_out
  k_conv<<<dim3(128, 8, 2), 256, 0, stream>>>(f_A, 512, f_A, 0, conv2_w,
                                              bn2_g, bn2_b, bn2_m, bn2_v, (float*)d_out);
}

// Round 3
// 2120.825 us; speedup vs baseline: 4.7101x; 4.7101x over previous
//
#include <hip/hip_runtime.h>
#include <hip/hip_bf16.h>
#include <math.h>

#define HW 16384
#define IMH 128
#define IMW 128

typedef _Float16 f16x8 __attribute__((ext_vector_type(8)));
typedef float f32x4 __attribute__((ext_vector_type(4)));

__device__ __forceinline__ void gload16(const void* g, void* l) {
  __builtin_amdgcn_global_load_lds(
      (const __attribute__((address_space(1))) void*)g,
      (__attribute__((address_space(3))) void*)l, 16, 0, 0);
}

// ---------------- logits = fd_w @ x + fd_b ----------------
__global__ __launch_bounds__(256) void k_logits(const float* __restrict__ x,
                                                const float* __restrict__ fd_w,
                                                const float* __restrict__ fd_b,
                                                float* __restrict__ probs) {
  __shared__ float w[256 * 32];
  int b = blockIdx.y;
  int pix = blockIdx.x * 256 + threadIdx.x;
  float acc[32];
#pragma unroll
  for (int k = 0; k < 32; k++) acc[k] = fd_b[k];
  const float* xp = x + (size_t)b * 512 * HW + pix;
  for (int half = 0; half < 2; half++) {
    int cbase = half * 256;
    __syncthreads();
    for (int i = threadIdx.x; i < 256 * 32; i += 256) {
      int c = i >> 5, k = i & 31;
      w[i] = fd_w[k * 512 + cbase + c];
    }
    __syncthreads();
    for (int c = 0; c < 256; c++) {
      float xv = xp[(size_t)(cbase + c) * HW];
#pragma unroll
      for (int k = 0; k < 32; k++) acc[k] += xv * w[c * 32 + k];
    }
  }
#pragma unroll
  for (int k = 0; k < 32; k++) probs[((size_t)(b * 32 + k)) * HW + pix] = acc[k];
}

// ---------------- softmax over spatial (16384) per (b,k) ----------------
__global__ __launch_bounds__(256) void k_softmax_sp(float* __restrict__ probs) {
  int row = blockIdx.x;
  float* p = probs + (size_t)row * HW;
  __shared__ float red[256];
  float mx = -1e30f;
  for (int i = threadIdx.x; i < HW; i += 256) mx = fmaxf(mx, p[i]);
  red[threadIdx.x] = mx;
  __syncthreads();
  for (int s = 128; s > 0; s >>= 1) {
    if (threadIdx.x < s) red[threadIdx.x] = fmaxf(red[threadIdx.x], red[threadIdx.x + s]);
    __syncthreads();
  }
  mx = red[0];
  __syncthreads();
  float sum = 0.f;
  for (int i = threadIdx.x; i < HW; i += 256) sum += expf(p[i] - mx);
  red[threadIdx.x] = sum;
  __syncthreads();
  for (int s = 128; s > 0; s >>= 1) {
    if (threadIdx.x < s) red[threadIdx.x] += red[threadIdx.x + s];
    __syncthreads();
  }
  float inv = 1.0f / red[0];
  for (int i = threadIdx.x; i < HW; i += 256) p[i] = expf(p[i] - mx) * inv;
}

// ---------------- pooled = leaky(mean 32x32 window) ----------------
__global__ __launch_bounds__(256) void k_pool(const float* __restrict__ x,
                                              float* __restrict__ pooled) {
  int b = blockIdx.z, ih = blockIdx.y, iw = blockIdx.x;
  for (int c = threadIdx.x; c < 512; c += 256) {
    const float* xp = x + ((size_t)(b * 512 + c) * IMH + ih * 32) * IMW + iw * 32;
    float s = 0.f;
    for (int r = 0; r < 32; r++)
      for (int cc = 0; cc < 32; cc++) s += xp[r * IMW + cc];
    s *= (1.0f / 1024.0f);
    if (s < 0.f) s *= 0.01f;
    pooled[(b * 512 + c) * 16 + ih * 4 + iw] = s;
  }
}

// ---------------- off / scl / ang heads ----------------
__global__ __launch_bounds__(256) void k_heads(const float* __restrict__ pooled,
                                               const float* __restrict__ off_w, const float* __restrict__ off_b,
                                               const float* __restrict__ scale_w, const float* __restrict__ scale_b,
                                               const float* __restrict__ angle_w, const float* __restrict__ angle_b,
                                               float* __restrict__ f_off, float* __restrict__ f_scl,
                                               float* __restrict__ f_ang) {
  int b = blockIdx.z, ih = blockIdx.y, iw = blockIdx.x;
  __shared__ float pl[512];
  int ij = ih * 4 + iw;
  for (int c = threadIdx.x; c < 512; c += 256) pl[c] = pooled[(b * 512 + c) * 16 + ij];
  __syncthreads();
  int t = threadIdx.x;
  if (t < 40) {
    const float* wt;
    float bias;
    if (t < 16) { wt = off_w + t * 512; bias = off_b[t]; }
    else if (t < 32) { int u = t - 16; wt = scale_w + u * 512; bias = scale_b[u]; }
    else { int u = t - 32; wt = angle_w + u * 512; bias = angle_b[u]; }
    float s = bias;
    for (int c = 0; c < 512; c++) s += pl[c] * wt[c];
    if (t < 16) {
      int n = t / 2, l = t % 2;
      f_off[((b * 8 + n) * 2 + l) * 16 + ij] = s * (1.0f / 32.0f);
    } else if (t < 32) {
      int u = t - 16;
      int n = u / 2, l = u % 2;
      f_scl[((b * 8 + n) * 2 + l) * 16 + ij] = s;
    } else {
      int n = t - 32;
      f_ang[(b * 8 + n) * 16 + ij] = s;
    }
  }
}

// ---------------- sampling grid ----------------
__global__ __launch_bounds__(256) void k_grid(const float* __restrict__ f_off,
                                              const float* __restrict__ f_scl,
                                              const float* __restrict__ f_ang,
                                              float* __restrict__ grid) {
  int p = blockIdx.y;
  int hw = blockIdx.x * 256 + threadIdx.x;
  int h = hw >> 7, w = hw & 127;
  int ih = h >> 5, r = h & 31, iw = w >> 5, cs = w & 31;
  int ij = ih * 4 + iw;
  float off0 = f_off[(p * 2 + 0) * 16 + ij], off1 = f_off[(p * 2 + 1) * 16 + ij];
  float scl0 = f_scl[(p * 2 + 0) * 16 + ij], scl1 = f_scl[(p * 2 + 1) * 16 + ij];
  float a = f_ang[p * 16 + ij];
  float sa = sinf(a), ca = cosf(a);
  float bwv = ((float)cs - 15.5f) * (2.0f / 127.0f);
  float bhv = ((float)r - 15.5f) * (2.0f / 127.0f);
  float wc0 = bwv * (scl0 + 1.0f);
  float wc1 = bhv * (scl1 + 1.0f);
  float wrw = -1.0f + 2.0f * ((float)(iw * 32) + 15.5f) / 127.0f;
  float wrh = -1.0f + 2.0f * ((float)(ih * 32) + 15.5f) / 127.0f;
  float c0 = wrw + (-wc1 * sa + wc0 * ca) + off0;
  float c1 = wrh + (wc1 * ca + wc0 * sa) + off1;
  size_t o = ((size_t)p * HW + hw) * 2;
  grid[o] = c0;
  grid[o + 1] = c1;
}

// ---------------- generic 512x512 1x1 conv (fp32) ----------------
__global__ __launch_bounds__(256) void k_gemm512(const float* __restrict__ X,
                                                 const float* __restrict__ Wt,
                                                 const float* __restrict__ bias,
                                                 float* __restrict__ Y) {
  __shared__ float lw[16][64];
  __shared__ float lx[16][64];
  int b = blockIdx.z;
  int m0 = blockIdx.y * 64;
  int n0 = blockIdx.x * 64;
  int tid = threadIdx.x;
  int tm = tid >> 4, tn = tid & 15;
  float acc[4][4] = {};
  const float* Xb = X + (size_t)b * 512 * HW;
  for (int c0 = 0; c0 < 512; c0 += 16) {
    {
      int m = tid >> 2, c4 = (tid & 3) * 4;
      const float* wp = Wt + (size_t)(m0 + m) * 512 + c0 + c4;
      float4 v = *reinterpret_cast<const float4*>(wp);
      lw[c4 + 0][m] = v.x;
      lw[c4 + 1][m] = v.y;
      lw[c4 + 2][m] = v.z;
      lw[c4 + 3][m] = v.w;
    }
    {
      int kk = tid >> 4, n4 = (tid & 15) * 4;
      const float* xp = Xb + (size_t)(c0 + kk) * HW + n0 + n4;
      *reinterpret_cast<float4*>(&lx[kk][n4]) = *reinterpret_cast<const float4*>(xp);
    }
    __syncthreads();
#pragma unroll
    for (int kk = 0; kk < 16; kk++) {
      float wv[4], xv[4];
      *reinterpret_cast<float4*>(wv) = *reinterpret_cast<const float4*>(&lw[kk][tm * 4]);
      *reinterpret_cast<float4*>(xv) = *reinterpret_cast<const float4*>(&lx[kk][tn * 4]);
#pragma unroll
      for (int i = 0; i < 4; i++)
#pragma unroll
        for (int j = 0; j < 4; j++) acc[i][j] += wv[i] * xv[j];
    }
    __syncthreads();
  }
#pragma unroll
  for (int i = 0; i < 4; i++) {
    int m = m0 + tm * 4 + i;
    float bv = bias[m];
    float4 vo = make_float4(acc[i][0] + bv, acc[i][1] + bv, acc[i][2] + bv, acc[i][3] + bv);
    *reinterpret_cast<float4*>(Y + ((size_t)b * 512 + m) * HW + n0 + tn * 4) = vo;
  }
}

// ---------------- bilinear grid-sample with zero padding ----------------
__global__ __launch_bounds__(256) void k_gsample(const float* __restrict__ img, int CH, int pmod,
                                                 const float* __restrict__ grid,
                                                 float* __restrict__ out) {
  int p = blockIdx.y;
  int hw = blockIdx.x * 256 + threadIdx.x;
  const float* ib = img + (size_t)(p % pmod) * CH * HW;
  float gx = grid[((size_t)p * HW + hw) * 2 + 0];
  float gy = grid[((size_t)p * HW + hw) * 2 + 1];
  gx = (gx + 1.0f) * 0.5f * 127.0f;
  gy = (gy + 1.0f) * 0.5f * 127.0f;
  float x0f = floorf(gx), y0f = floorf(gy);
  float wx1 = gx - x0f, wx0 = 1.0f - wx1;
  float wy1 = gy - y0f, wy0 = 1.0f - wy1;
  int x0 = (int)x0f, y0 = (int)y0f;
  bool vx0 = (x0f >= 0.f) && (x0f <= 127.f);
  bool vx1 = (x0f + 1.0f >= 0.f) && (x0f + 1.0f <= 127.f);
  bool vy0 = (y0f >= 0.f) && (y0f <= 127.f);
  bool vy1 = (y0f + 1.0f >= 0.f) && (y0f + 1.0f <= 127.f);
  int x0c = min(max(x0, 0), 127), x1c = min(max(x0 + 1, 0), 127);
  int y0c = min(max(y0, 0), 127), y1c = min(max(y0 + 1, 0), 127);
  float w00 = wx0 * wy0 * ((vx0 && vy0) ? 1.f : 0.f);
  float w01 = wx1 * wy0 * ((vx1 && vy0) ? 1.f : 0.f);
  float w10 = wx0 * wy1 * ((vx0 && vy1) ? 1.f : 0.f);
  float w11 = wx1 * wy1 * ((vx1 && vy1) ? 1.f : 0.f);
  int o00 = y0c * IMW + x0c, o01 = y0c * IMW + x1c;
  int o10 = y1c * IMW + x0c, o11 = y1c * IMW + x1c;
  for (int c = 0; c < CH; c++) {
    const float* ic = ib + (size_t)c * HW;
    float v = ic[o00] * w00 + ic[o01] * w01 + ic[o10] * w10 + ic[o11] * w11;
    out[((size_t)p * CH + c) * HW + hw] = v;
  }
}

// ---------------- lc[p*16+win][k][d] = sum_s tp[k][s]*tx[d][s] ----------------
__global__ __launch_bounds__(256) void k_lc(const float* __restrict__ tx,
                                            const float* __restrict__ tp,
                                            float* __restrict__ lc) {
  int idx2 = blockIdx.x;
  int p = idx2 >> 4, win = idx2 & 15;
  int ih = win >> 2, iw = win & 3;
  __shared__ float ltx[64][65];
  __shared__ float ltp[64][33];
  int tid = threadIdx.x;
  int k = tid >> 3, dg = tid & 7;
  float acc[8] = {};
  const float* txp = tx + (size_t)p * 64 * HW;
  const float* tpp = tp + (size_t)p * 32 * HW;
  int base = (ih * 32) * IMW + iw * 32;
  for (int s0 = 0; s0 < 1024; s0 += 64) {
#pragma unroll
    for (int i = 0; i < 16; i++) {
      int linear = tid + i * 256;
      int d = linear >> 6, sl = linear & 63;
      int s = s0 + sl;
      int pix = base + (s >> 5) * IMW + (s & 31);
      ltx[sl][d] = txp[(size_t)d * HW + pix];
    }
#pragma unroll
    for (int i = 0; i < 8; i++) {
      int linear = tid + i * 256;
      int kk = linear >> 6, sl = linear & 63;
      int s = s0 + sl;
      int pix = base + (s >> 5) * IMW + (s & 31);
      ltp[sl][kk] = tpp[(size_t)kk * HW + pix];
    }
    __syncthreads();
    for (int sl = 0; sl < 64; sl++) {
      float tv = ltp[sl][k];
#pragma unroll
      for (int j = 0; j < 8; j++) acc[j] += tv * ltx[sl][dg * 8 + j];
    }
    __syncthreads();
  }
  float* lp = lc + ((size_t)idx2 * 32 + k) * 64 + dg * 8;
#pragma unroll
  for (int j = 0; j < 8; j++) lp[j] = acc[j];
}

// ---------------- v2[j][k][o] = gc[j][k]·v_w[o] + v_b[o] ----------------
__global__ __launch_bounds__(256) void k_v2(const float* __restrict__ gc,
                                            const float* __restrict__ v_w,
                                            const float* __restrict__ v_b,
                                            float* __restrict__ v2) {
  int j = blockIdx.x >> 5, k = blockIdx.x & 31;
  __shared__ float g[512];
  for (int c = threadIdx.x; c < 512; c += 256) g[c] = gc[((size_t)j * 32 + k) * 512 + c];
  __syncthreads();
  for (int o = threadIdx.x; o < 512; o += 256) {
    float s = v_b[o];
    const float* wp = v_w + (size_t)o * 512;
    for (int c = 0; c < 512; c++) s += g[c] * wp[c];
    v2[((size_t)j * 32 + k) * 512 + o] = s;
  }
}

// ---------------- attention per (b, win, n) ----------------
__global__ __launch_bounds__(256) void k_attn(const float* __restrict__ Yq,
                                              const float* __restrict__ lc,
                                              const float* __restrict__ v2,
                                              float* __restrict__ att) {
  int n = blockIdx.x, win = blockIdx.y, b = blockIdx.z;
  int ih = win >> 2, iw = win & 3;
  __shared__ float llc[32 * 64];
  __shared__ float lv[32 * 64];
  int bnw = b * 16 + win;
  const float* lcp = lc + (size_t)(bnw * 8 + n) * 2048;
  const float* vp = v2 + (size_t)(bnw & 1) * 32 * 512 + n * 64;
  for (int i = threadIdx.x; i < 2048; i += 256) {
    llc[i] = lcp[i];
    int k = i >> 6, d = i & 63;
    lv[i] = vp[(size_t)k * 512 + d];
  }
  __syncthreads();
  const float scale = 0.125f;
  for (int rep = 0; rep < 4; rep++) {
    int s = threadIdx.x + rep * 256;
    int pix = (ih * 32 + (s >> 5)) * IMW + iw * 32 + (s & 31);
    const float* qp = Yq + ((size_t)(b * 512 + n * 64)) * HW + pix;
    float q[64];
#pragma unroll
    for (int d = 0; d < 64; d++) q[d] = qp[(size_t)d * HW];
    float dots[32];
#pragma unroll
    for (int k = 0; k < 32; k++) {
      float s2 = 0.f;
#pragma unroll
      for (int d = 0; d < 64; d++) s2 += q[d] * llc[k * 64 + d];
      dots[k] = s2 * scale;
    }
    float mx = -1e30f;
#pragma unroll
    for (int k = 0; k < 32; k++) mx = fmaxf(mx, dots[k]);
    float sum = 0.f;
#pragma unroll
    for (int k = 0; k < 32; k++) {
      dots[k] = expf(dots[k] - mx);
      sum += dots[k];
    }
    float inv = 1.0f / sum;
    float outv[64];
#pragma unroll
    for (int d = 0; d < 64; d++) outv[d] = 0.f;
#pragma unroll
    for (int k = 0; k < 32; k++) {
      float a = dots[k] * inv;
#pragma unroll
      for (int d = 0; d < 64; d++) outv[d] += a * lv[k * 64 + d];
    }
    float* op = att + ((size_t)(b * 512 + n * 64)) * HW + pix;
#pragma unroll
    for (int d = 0; d < 64; d++) op[(size_t)d * HW] = outv[d];
  }
}

// ---------------- NCHW fp32 -> HWC f16 (octet-swizzled, key=(w+1)&7) ----------------
// out[b][h][w][c_swz] where c_swz swaps 8-ch octets within each 64-ch group:
// oct' = oct ^ ((w+1)&7). This makes conv fragment ds_read_b128 conflict-free
// while keeping global_load_lds staging linear (m173 pre-swizzled-source pattern).
__global__ __launch_bounds__(256) void k_to_hwc(const float* __restrict__ in,
                                                _Float16* __restrict__ out) {
  int h = blockIdx.x, b = blockIdx.y;
  __shared__ _Float16 t[128 * 128];  // [c-chunk][w]
  for (int cc = 0; cc < 4; cc++) {
    int c0 = cc * 128;
    __syncthreads();
    for (int i = 0; i < 16; i++) {
      int linear = i * 256 + threadIdx.x;  // 4096 float4 loads
      int c = linear >> 5, w4 = linear & 31;
      float4 v = *reinterpret_cast<const float4*>(
          in + ((size_t)(b * 512 + c0 + c) * IMH + h) * IMW + w4 * 4);
      _Float16* d = t + c * 128 + w4 * 4;
      d[0] = (_Float16)v.x; d[1] = (_Float16)v.y;
      d[2] = (_Float16)v.z; d[3] = (_Float16)v.w;
    }
    __syncthreads();
    for (int i = 0; i < 8; i++) {
      int linear = i * 256 + threadIdx.x;  // 2048 tasks: (octet j, pixel w)
      int j = linear >> 7, w = linear & 127;
      _Float16 v[8];
#pragma unroll
      for (int u = 0; u < 8; u++) v[u] = t[(j * 8 + u) * 128 + w];
      int c = c0 + j * 8;
      int key = (w + 1) & 7;
      int cs = (c & ~63) | (((((c >> 3) & 7) ^ key) & 7) << 3);
      *reinterpret_cast<f16x8*>(out + (((size_t)(b * IMH + h) * IMW + w) * 512) + cs) =
          *reinterpret_cast<const f16x8*>(v);
    }
  }
}

// ---------------- conv weights [o][c][3][3] fp32 -> [kk][o][c_swz] f16 (key=o&7) ----------------
__global__ __launch_bounds__(256) void k_wxform(const float* __restrict__ w,
                                                _Float16* __restrict__ o_, int Cout, int Cin,
                                                int total) {
  int idx = blockIdx.x * 256 + threadIdx.x;
  if (idx >= total) return;
  int c = idx % Cin;
  int t2 = idx / Cin;
  int oc = t2 % Cout;
  int kk = t2 / Cout;
  int ky = kk / 3, kx = kk % 3;
  float v = w[(((size_t)oc * Cin + c) * 3 + ky) * 3 + kx];
  int key = oc & 7;
  int cs = (c & ~63) | (((((c >> 3) & 7) ^ key) & 7) << 3) | (c & 7);
  o_[((size_t)kk * Cout + oc) * Cin + cs] = (_Float16)v;
}

// ---------------- MFMA 3x3 conv + BN + ReLU ----------------
// Tile: 128 out-channels x 128 pixels (one image row). 4 waves, each 64x64.
// B operand = HWC f16 image (pre-swizzled), staged with 1-px zero halo so the
// kx shift is an LDS row offset. A operand = transformed weights.
__global__ __launch_bounds__(256) void k_conv_mfma(
    const _Float16* __restrict__ srcA, const _Float16* __restrict__ srcB,
    int CA, int CB,
    const _Float16* __restrict__ wT,
    const float* __restrict__ bn_g, const float* __restrict__ bn_b,
    const float* __restrict__ bn_m, const float* __restrict__ bn_v,
    float* __restrict__ out_f32, _Float16* __restrict__ out_hwc) {
  int mt = blockIdx.x;   // out-channel tile (0..3)
  int h = blockIdx.y;    // output row
  int b = blockIdx.z;
  int Cin = CA + CB;
  __shared__ _Float16 ldsA[128 * 64];  // [o][c] octet-swizzled (key o&7)
  __shared__ _Float16 ldsB[130 * 64];  // [w+1][c] octet-swizzled (key (w+1)&7), rows 0/129 = halo
  int tid = threadIdx.x;
  int wave = tid >> 6, lane = tid & 63;
  int wr = wave >> 1, wc = wave & 1;
  int l15 = lane & 15, l4 = lane >> 4;
  f32x4 acc[4][4] = {};
  // zero halo rows once (never overwritten by staging)
  if (tid < 32) ((float*)ldsB)[tid] = 0.f;
  else if (tid < 64) ((float*)ldsB)[129 * 32 + (tid - 32)] = 0.f;

  const int nc = Cin >> 6;
  for (int ky = 0; ky < 3; ky++) {
    int hh = h + ky - 1;
    if (hh < 0 || hh > 127) continue;
    for (int ci = 0; ci < nc; ci++) {
      int c0 = ci << 6;
      const _Float16* src;
      int cc0, Cbuf;
      if (c0 < CA) { src = srcA; cc0 = c0; Cbuf = CA; }
      else { src = srcB; cc0 = c0 - CA; Cbuf = CB; }
      // stage B: 128 px rows x 128B (16 x 1KB wave-chunks), linear LDS
      for (int it = 0; it < 4; it++) {
        int q = it * 4 + wave;
        gload16(src + (((size_t)(b * IMH + hh) * IMW + q * 8 + (lane >> 3)) * Cbuf +
                       cc0 + (lane & 7) * 8),
                ldsB + 64 + q * 512);
      }
      for (int kx = 0; kx < 3; kx++) {
        const _Float16* wbase =
            wT + ((size_t)((ky * 3 + kx) * 512 + mt * 128)) * Cin + c0;
        for (int it = 0; it < 4; it++) {
          int q = it * 4 + wave;
          gload16(wbase + (size_t)(q * 8 + (lane >> 3)) * Cin + (lane & 7) * 8,
                  ldsA + q * 512);
        }
        __syncthreads();  // drains vmcnt: A (and B at kx=0) ready
#pragma unroll
        for (int ks = 0; ks < 2; ks++) {
          f16x8 af[4], bf[4];
#pragma unroll
          for (int m = 0; m < 4; m++) {
            int o = wr * 64 + m * 16 + l15;
            int oct = (ks * 4 + l4) ^ (o & 7);
            af[m] = *reinterpret_cast<const f16x8*>(ldsA + o * 64 + oct * 8);
          }
#pragma unroll
          for (int n = 0; n < 4; n++) {
            int r = wc * 64 + n * 16 + l15 + kx;  // shifted tile row
            int oct = (ks * 4 + l4) ^ (r & 7);
            bf[n] = *reinterpret_cast<const f16x8*>(ldsB + r * 64 + oct * 8);
          }
#pragma unroll
          for (int m = 0; m < 4; m++)
#pragma unroll
            for (int n = 0; n < 4; n++)
              acc[m][n] = __builtin_amdgcn_mfma_f32_16x16x32_f16(af[m], bf[n],
                                                                 acc[m][n], 0, 0, 0);
        }
        __syncthreads();  // protect ldsA (and ldsB at kx=2) before restage
      }
    }
  }
  // epilogue: BN + ReLU; D layout: col(pixel)=lane&15, row(o)=(lane>>4)*4+reg
#pragma unroll
  for (int m = 0; m < 4; m++) {
#pragma unroll
    for (int n = 0; n < 4; n++) {
      f32x4 v = acc[m][n];
      int px = wc * 64 + n * 16 + l15;
      int obase = mt * 128 + wr * 64 + m * 16 + l4 * 4;
      if (out_hwc) {
        _Float16 hv[4];
#pragma unroll
        for (int r = 0; r < 4; r++) {
          int o = obase + r;
          float sc = bn_g[o] * rsqrtf(bn_v[o] + 1e-5f);
          float sh = bn_b[o] - bn_m[o] * sc;
          hv[r] = (_Float16)fmaxf(v[r] * sc + sh, 0.f);
        }
        int key = (px + 1) & 7;
        int cs = (obase & ~63) | (((((obase >> 3) & 7) ^ key) & 7) << 3) | (obase & 7);
        *reinterpret_cast<uint2*>(out_hwc + ((size_t)(b * IMH + h) * IMW + px) * 512 + cs) =
            *reinterpret_cast<const uint2*>(hv);
      } else {
#pragma unroll
        for (int r = 0; r < 4; r++) {
          int o = obase + r;
          float sc = bn_g[o] * rsqrtf(bn_v[o] + 1e-5f);
          float sh = bn_b[o] - bn_m[o] * sc;
          out_f32[((size_t)(b * 512 + o)) * HW + h * IMW + px] =
              fmaxf(v[r] * sc + sh, 0.f);
        }
      }
    }
  }
}

extern "C" void kernel_launch(void* const* d_in, const int* in_sizes, int n_in,
                              void* d_out, int out_size, void* d_ws, size_t ws_size,
                              hipStream_t stream) {
  const float* x = (const float*)d_in[0];
  const float* gc = (const float*)d_in[1];
  const float* fd_w = (const float*)d_in[2];
  const float* fd_b = (const float*)d_in[3];
  const float* off_w = (const float*)d_in[4];
  const float* off_b = (const float*)d_in[5];
  const float* scale_w = (const float*)d_in[6];
  const float* scale_b = (const float*)d_in[7];
  const float* angle_w = (const float*)d_in[8];
  const float* angle_b = (const float*)d_in[9];
  const float* q_w = (const float*)d_in[10];
  const float* q_b = (const float*)d_in[11];
  const float* k_w = (const float*)d_in[12];
  const float* k_b = (const float*)d_in[13];
  const float* v_w = (const float*)d_in[14];
  const float* v_b = (const float*)d_in[15];
  const float* proj_w = (const float*)d_in[16];
  const float* proj_b = (const float*)d_in[17];
  const float* conv1_w = (const float*)d_in[18];
  const float* bn1_g = (const float*)d_in[19];
  const float* bn1_b = (const float*)d_in[20];
  const float* bn1_m = (const float*)d_in[21];
  const float* bn1_v = (const float*)d_in[22];
  const float* conv2_w = (const float*)d_in[23];
  const float* bn2_g = (const float*)d_in[24];
  const float* bn2_b = (const float*)d_in[25];
  const float* bn2_m = (const float*)d_in[26];
  const float* bn2_v = (const float*)d_in[27];

  // Workspace layout: identical 243.5 MB footprint to the round-0 version that
  // passed. f16 buffers alias proven-dead fp32 regions (see schedule below).
  float* ws = (float*)d_ws;
  float* f_probs = ws; ws += 1048576;   // (B,32,HW)
  float* f_grid = ws; ws += 524288;     // (16,HW,2)
  float* f_pooled = ws; ws += 16384;
  float* f_off = ws; ws += 512;
  float* f_scl = ws; ws += 512;
  float* f_ang = ws; ws += 256;
  float* f_lc = ws; ws += 524288;       // (256,32,64)
  float* f_v2 = ws; ws += 32768;        // (2,32,512)
  float* f_tp = ws; ws += 8388608;      // (16,32,HW); later x_hwc (f16, exact fit)
  float* f_A = ws; ws += 16777216;      // key_feat; later h1_hwc (f16)
  float* f_B = ws; ws += 16777216;      // Yq; later ctx_hwc (lower) + wT1/wT2 (upper)
  float* f_C = ws; ws += 16777216;      // tx; later ctx fp32

  _Float16* x_hwc = (_Float16*)f_tp;                  // 2*HW*512 f16 = 8388608 floats
  _Float16* h1_hwc = (_Float16*)f_A;                  // 8388608 floats used
  _Float16* ctx_hwc = (_Float16*)f_B;                 // 8388608 floats (lower half)
  _Float16* wT1 = (_Float16*)(f_B + 8388608);         // 9*512*1024 f16 = 2359296 floats
  _Float16* wT2 = (_Float16*)(f_B + 8388608 + 2359296); // 9*512*512 f16 = 1179648 floats
  float* f_att = (float*)d_out;

  k_logits<<<dim3(64, 2), 256, 0, stream>>>(x, fd_w, fd_b, f_probs);
  k_softmax_sp<<<dim3(64), 256, 0, stream>>>(f_probs);
  k_pool<<<dim3(4, 4, 2), 256, 0, stream>>>(x, f_pooled);
  k_heads<<<dim3(4, 4, 2), 256, 0, stream>>>(f_pooled, off_w, off_b, scale_w, scale_b,
                                             angle_w, angle_b, f_off, f_scl, f_ang);
  k_grid<<<dim3(64, 16), 256, 0, stream>>>(f_off, f_scl, f_ang, f_grid);
  k_gemm512<<<dim3(256, 8, 2), 256, 0, stream>>>(x, k_w, k_b, f_A);
  k_gemm512<<<dim3(256, 8, 2), 256, 0, stream>>>(x, q_w, q_b, f_B);
  k_gsample<<<dim3(64, 16), 256, 0, stream>>>(f_A, 64, 16, f_grid, f_C);
  k_gsample<<<dim3(64, 16), 256, 0, stream>>>(f_probs, 32, 2, f_grid, f_tp);
  k_lc<<<dim3(256), 256, 0, stream>>>(f_C, f_tp, f_lc);
  // f_tp dead -> build x_hwc in its place
  k_to_hwc<<<dim3(128, 2), 256, 0, stream>>>(x, x_hwc);
  k_v2<<<dim3(64), 256, 0, stream>>>(gc, v_w, v_b, f_v2);
  k_attn<<<dim3(8, 16, 2), 256, 0, stream>>>(f_B, f_lc, f_v2, f_att);
  // f_B (Yq) dead -> weight transforms into its upper half
  k_wxform<<<dim3(18432), 256, 0, stream>>>(conv1_w, wT1, 512, 1024, 9 * 512 * 1024);
  k_wxform<<<dim3(9216), 256, 0, stream>>>(conv2_w, wT2, 512, 512, 9 * 512 * 512);
  k_gemm512<<<dim3(256, 8, 2), 256, 0, stream>>>(f_att, proj_w, proj_b, f_C);
  // ctx fp32 -> HWC f16 into f_B lower half
  k_to_hwc<<<dim3(128, 2), 256, 0, stream>>>(f_C, ctx_hwc);
  // conv1: concat(x, ctx) -> h1 (HWC f16, into f_A region)
  k_conv_mfma<<<dim3(4, 128, 2), 256, 0, stream>>>(x_hwc, ctx_hwc, 512, 512, wT1,
                                                   bn1_g, bn1_b, bn1_m, bn1_v,
                                                   nullptr, h1_hwc);
  // conv2: h1 -> d_out (NCHW fp32)
  k_conv_mfma<<<dim3(4, 128, 2), 256, 0, stream>>>(h1_hwc, h1_hwc, 512, 0, wT2,
                                                   bn2_g, bn2_b, bn2_m, bn2_v,
                                                   (float*)d_out, nullptr);
}

// Round 4
// 1490.482 us; speedup vs baseline: 6.7020x; 1.4229x over previous
//
#include <hip/hip_runtime.h>
#include <hip/hip_bf16.h>
#include <math.h>

#define HW 16384
#define IMH 128
#define IMW 128

typedef _Float16 f16x8 __attribute__((ext_vector_type(8)));
typedef float f32x4 __attribute__((ext_vector_type(4)));

__device__ __forceinline__ void gload16(const void* g, void* l) {
  __builtin_amdgcn_global_load_lds(
      (const __attribute__((address_space(1))) void*)g,
      (__attribute__((address_space(3))) void*)l, 16, 0, 0);
}

// ---------------- logits = fd_w @ x + fd_b ----------------
__global__ __launch_bounds__(256) void k_logits(const float* __restrict__ x,
                                                const float* __restrict__ fd_w,
                                                const float* __restrict__ fd_b,
                                                float* __restrict__ probs) {
  __shared__ float w[256 * 32];
  int b = blockIdx.y;
  int pix = blockIdx.x * 256 + threadIdx.x;
  float acc[32];
#pragma unroll
  for (int k = 0; k < 32; k++) acc[k] = fd_b[k];
  const float* xp = x + (size_t)b * 512 * HW + pix;
  for (int half = 0; half < 2; half++) {
    int cbase = half * 256;
    __syncthreads();
    for (int i = threadIdx.x; i < 256 * 32; i += 256) {
      int c = i >> 5, k = i & 31;
      w[i] = fd_w[k * 512 + cbase + c];
    }
    __syncthreads();
    for (int c = 0; c < 256; c++) {
      float xv = xp[(size_t)(cbase + c) * HW];
#pragma unroll
      for (int k = 0; k < 32; k++) acc[k] += xv * w[c * 32 + k];
    }
  }
#pragma unroll
  for (int k = 0; k < 32; k++) probs[((size_t)(b * 32 + k)) * HW + pix] = acc[k];
}

// ---------------- softmax over spatial (16384) per (b,k) ----------------
__global__ __launch_bounds__(256) void k_softmax_sp(float* __restrict__ probs) {
  int row = blockIdx.x;
  float* p = probs + (size_t)row * HW;
  __shared__ float red[256];
  float mx = -1e30f;
  for (int i = threadIdx.x; i < HW; i += 256) mx = fmaxf(mx, p[i]);
  red[threadIdx.x] = mx;
  __syncthreads();
  for (int s = 128; s > 0; s >>= 1) {
    if (threadIdx.x < s) red[threadIdx.x] = fmaxf(red[threadIdx.x], red[threadIdx.x + s]);
    __syncthreads();
  }
  mx = red[0];
  __syncthreads();
  float sum = 0.f;
  for (int i = threadIdx.x; i < HW; i += 256) sum += expf(p[i] - mx);
  red[threadIdx.x] = sum;
  __syncthreads();
  for (int s = 128; s > 0; s >>= 1) {
    if (threadIdx.x < s) red[threadIdx.x] += red[threadIdx.x + s];
    __syncthreads();
  }
  float inv = 1.0f / red[0];
  for (int i = threadIdx.x; i < HW; i += 256) p[i] = expf(p[i] - mx) * inv;
}

// ---------------- pooled = leaky(mean 32x32 window) ----------------
__global__ __launch_bounds__(256) void k_pool(const float* __restrict__ x,
                                              float* __restrict__ pooled) {
  int b = blockIdx.z, ih = blockIdx.y, iw = blockIdx.x;
  for (int c = threadIdx.x; c < 512; c += 256) {
    const float* xp = x + ((size_t)(b * 512 + c) * IMH + ih * 32) * IMW + iw * 32;
    float s = 0.f;
    for (int r = 0; r < 32; r++)
      for (int cc = 0; cc < 32; cc++) s += xp[r * IMW + cc];
    s *= (1.0f / 1024.0f);
    if (s < 0.f) s *= 0.01f;
    pooled[(b * 512 + c) * 16 + ih * 4 + iw] = s;
  }
}

// ---------------- off / scl / ang heads ----------------
__global__ __launch_bounds__(256) void k_heads(const float* __restrict__ pooled,
                                               const float* __restrict__ off_w, const float* __restrict__ off_b,
                                               const float* __restrict__ scale_w, const float* __restrict__ scale_b,
                                               const float* __restrict__ angle_w, const float* __restrict__ angle_b,
                                               float* __restrict__ f_off, float* __restrict__ f_scl,
                                               float* __restrict__ f_ang) {
  int b = blockIdx.z, ih = blockIdx.y, iw = blockIdx.x;
  __shared__ float pl[512];
  int ij = ih * 4 + iw;
  for (int c = threadIdx.x; c < 512; c += 256) pl[c] = pooled[(b * 512 + c) * 16 + ij];
  __syncthreads();
  int t = threadIdx.x;
  if (t < 40) {
    const float* wt;
    float bias;
    if (t < 16) { wt = off_w + t * 512; bias = off_b[t]; }
    else if (t < 32) { int u = t - 16; wt = scale_w + u * 512; bias = scale_b[u]; }
    else { int u = t - 32; wt = angle_w + u * 512; bias = angle_b[u]; }
    float s = bias;
    for (int c = 0; c < 512; c++) s += pl[c] * wt[c];
    if (t < 16) {
      int n = t / 2, l = t % 2;
      f_off[((b * 8 + n) * 2 + l) * 16 + ij] = s * (1.0f / 32.0f);
    } else if (t < 32) {
      int u = t - 16;
      int n = u / 2, l = u % 2;
      f_scl[((b * 8 + n) * 2 + l) * 16 + ij] = s;
    } else {
      int n = t - 32;
      f_ang[(b * 8 + n) * 16 + ij] = s;
    }
  }
}

// ---------------- sampling grid ----------------
__global__ __launch_bounds__(256) void k_grid(const float* __restrict__ f_off,
                                              const float* __restrict__ f_scl,
                                              const float* __restrict__ f_ang,
                                              float* __restrict__ grid) {
  int p = blockIdx.y;
  int hw = blockIdx.x * 256 + threadIdx.x;
  int h = hw >> 7, w = hw & 127;
  int ih = h >> 5, r = h & 31, iw = w >> 5, cs = w & 31;
  int ij = ih * 4 + iw;
  float off0 = f_off[(p * 2 + 0) * 16 + ij], off1 = f_off[(p * 2 + 1) * 16 + ij];
  float scl0 = f_scl[(p * 2 + 0) * 16 + ij], scl1 = f_scl[(p * 2 + 1) * 16 + ij];
  float a = f_ang[p * 16 + ij];
  float sa = sinf(a), ca = cosf(a);
  float bwv = ((float)cs - 15.5f) * (2.0f / 127.0f);
  float bhv = ((float)r - 15.5f) * (2.0f / 127.0f);
  float wc0 = bwv * (scl0 + 1.0f);
  float wc1 = bhv * (scl1 + 1.0f);
  float wrw = -1.0f + 2.0f * ((float)(iw * 32) + 15.5f) / 127.0f;
  float wrh = -1.0f + 2.0f * ((float)(ih * 32) + 15.5f) / 127.0f;
  float c0 = wrw + (-wc1 * sa + wc0 * ca) + off0;
  float c1 = wrh + (wc1 * ca + wc0 * sa) + off1;
  size_t o = ((size_t)p * HW + hw) * 2;
  grid[o] = c0;
  grid[o + 1] = c1;
}

// ---------------- bilinear grid-sample with zero padding ----------------
__global__ __launch_bounds__(256) void k_gsample(const float* __restrict__ img, int CH, int pmod,
                                                 const float* __restrict__ grid,
                                                 float* __restrict__ out) {
  int p = blockIdx.y;
  int hw = blockIdx.x * 256 + threadIdx.x;
  const float* ib = img + (size_t)(p % pmod) * CH * HW;
  float gx = grid[((size_t)p * HW + hw) * 2 + 0];
  float gy = grid[((size_t)p * HW + hw) * 2 + 1];
  gx = (gx + 1.0f) * 0.5f * 127.0f;
  gy = (gy + 1.0f) * 0.5f * 127.0f;
  float x0f = floorf(gx), y0f = floorf(gy);
  float wx1 = gx - x0f, wx0 = 1.0f - wx1;
  float wy1 = gy - y0f, wy0 = 1.0f - wy1;
  int x0 = (int)x0f, y0 = (int)y0f;
  bool vx0 = (x0f >= 0.f) && (x0f <= 127.f);
  bool vx1 = (x0f + 1.0f >= 0.f) && (x0f + 1.0f <= 127.f);
  bool vy0 = (y0f >= 0.f) && (y0f <= 127.f);
  bool vy1 = (y0f + 1.0f >= 0.f) && (y0f + 1.0f <= 127.f);
  int x0c = min(max(x0, 0), 127), x1c = min(max(x0 + 1, 0), 127);
  int y0c = min(max(y0, 0), 127), y1c = min(max(y0 + 1, 0), 127);
  float w00 = wx0 * wy0 * ((vx0 && vy0) ? 1.f : 0.f);
  float w01 = wx1 * wy0 * ((vx1 && vy0) ? 1.f : 0.f);
  float w10 = wx0 * wy1 * ((vx0 && vy1) ? 1.f : 0.f);
  float w11 = wx1 * wy1 * ((vx1 && vy1) ? 1.f : 0.f);
  int o00 = y0c * IMW + x0c, o01 = y0c * IMW + x1c;
  int o10 = y1c * IMW + x0c, o11 = y1c * IMW + x1c;
  for (int c = 0; c < CH; c++) {
    const float* ic = ib + (size_t)c * HW;
    float v = ic[o00] * w00 + ic[o01] * w01 + ic[o10] * w10 + ic[o11] * w11;
    out[((size_t)p * CH + c) * HW + hw] = v;
  }
}

// ---------------- lc[p*16+win][k][d] = sum_s tp[k][s]*tx[d][s] ----------------
__global__ __launch_bounds__(256) void k_lc(const float* __restrict__ tx,
                                            const float* __restrict__ tp,
                                            float* __restrict__ lc) {
  int idx2 = blockIdx.x;
  int p = idx2 >> 4, win = idx2 & 15;
  int ih = win >> 2, iw = win & 3;
  __shared__ float ltx[64][65];
  __shared__ float ltp[64][33];
  int tid = threadIdx.x;
  int k = tid >> 3, dg = tid & 7;
  float acc[8] = {};
  const float* txp = tx + (size_t)p * 64 * HW;
  const float* tpp = tp + (size_t)p * 32 * HW;
  int base = (ih * 32) * IMW + iw * 32;
  for (int s0 = 0; s0 < 1024; s0 += 64) {
#pragma unroll
    for (int i = 0; i < 16; i++) {
      int linear = tid + i * 256;
      int d = linear >> 6, sl = linear & 63;
      int s = s0 + sl;
      int pix = base + (s >> 5) * IMW + (s & 31);
      ltx[sl][d] = txp[(size_t)d * HW + pix];
    }
#pragma unroll
    for (int i = 0; i < 8; i++) {
      int linear = tid + i * 256;
      int kk = linear >> 6, sl = linear & 63;
      int s = s0 + sl;
      int pix = base + (s >> 5) * IMW + (s & 31);
      ltp[sl][kk] = tpp[(size_t)kk * HW + pix];
    }
    __syncthreads();
    for (int sl = 0; sl < 64; sl++) {
      float tv = ltp[sl][k];
#pragma unroll
      for (int j = 0; j < 8; j++) acc[j] += tv * ltx[sl][dg * 8 + j];
    }
    __syncthreads();
  }
  float* lp = lc + ((size_t)idx2 * 32 + k) * 64 + dg * 8;
#pragma unroll
  for (int j = 0; j < 8; j++) lp[j] = acc[j];
}

// ---------------- v2[j][k][o] = gc[j][k]·v_w[o] + v_b[o] ----------------
__global__ __launch_bounds__(256) void k_v2(const float* __restrict__ gc,
                                            const float* __restrict__ v_w,
                                            const float* __restrict__ v_b,
                                            float* __restrict__ v2) {
  int j = blockIdx.x >> 5, k = blockIdx.x & 31;
  __shared__ float g[512];
  for (int c = threadIdx.x; c < 512; c += 256) g[c] = gc[((size_t)j * 32 + k) * 512 + c];
  __syncthreads();
  for (int o = threadIdx.x; o < 512; o += 256) {
    float s = v_b[o];
    const float* wp = v_w + (size_t)o * 512;
    for (int c = 0; c < 512; c++) s += g[c] * wp[c];
    v2[((size_t)j * 32 + k) * 512 + o] = s;
  }
}

// ---------------- attention per (b, win, n); writes att in HWC f16 swizzled ----------------
__global__ __launch_bounds__(256) void k_attn(const float* __restrict__ Yq,
                                              const float* __restrict__ lc,
                                              const float* __restrict__ v2,
                                              _Float16* __restrict__ att) {
  int n = blockIdx.x, win = blockIdx.y, b = blockIdx.z;
  int ih = win >> 2, iw = win & 3;
  __shared__ float llc[32 * 64];
  __shared__ float lv[32 * 64];
  int bnw = b * 16 + win;
  const float* lcp = lc + (size_t)(bnw * 8 + n) * 2048;
  const float* vp = v2 + (size_t)(bnw & 1) * 32 * 512 + n * 64;
  for (int i = threadIdx.x; i < 2048; i += 256) {
    llc[i] = lcp[i];
    int k = i >> 6, d = i & 63;
    lv[i] = vp[(size_t)k * 512 + d];
  }
  __syncthreads();
  const float scale = 0.125f;
  for (int rep = 0; rep < 4; rep++) {
    int s = threadIdx.x + rep * 256;
    int w = iw * 32 + (s & 31);
    int pix = (ih * 32 + (s >> 5)) * IMW + w;
    const float* qp = Yq + ((size_t)(b * 512 + n * 64)) * HW + pix;
    float q[64];
#pragma unroll
    for (int d = 0; d < 64; d++) q[d] = qp[(size_t)d * HW];
    float dots[32];
#pragma unroll
    for (int k = 0; k < 32; k++) {
      float s2 = 0.f;
#pragma unroll
      for (int d = 0; d < 64; d++) s2 += q[d] * llc[k * 64 + d];
      dots[k] = s2 * scale;
    }
    float mx = -1e30f;
#pragma unroll
    for (int k = 0; k < 32; k++) mx = fmaxf(mx, dots[k]);
    float sum = 0.f;
#pragma unroll
    for (int k = 0; k < 32; k++) {
      dots[k] = expf(dots[k] - mx);
      sum += dots[k];
    }
    float inv = 1.0f / sum;
    float outv[64];
#pragma unroll
    for (int d = 0; d < 64; d++) outv[d] = 0.f;
#pragma unroll
    for (int k = 0; k < 32; k++) {
      float a = dots[k] * inv;
#pragma unroll
      for (int d = 0; d < 64; d++) outv[d] += a * lv[k * 64 + d];
    }
    // write HWC f16, octet-swizzled with key=(w+1)&7; channel group = head n
    int key = (w + 1) & 7;
    _Float16* ob = att + ((size_t)(b * HW) + pix) * 512 + n * 64;
#pragma unroll
    for (int u = 0; u < 8; u++) {
      _Float16 hv[8];
#pragma unroll
      for (int j = 0; j < 8; j++) hv[j] = (_Float16)outv[u * 8 + j];
      *reinterpret_cast<f16x8*>(ob + ((u ^ key) << 3)) = *reinterpret_cast<const f16x8*>(hv);
    }
  }
}

// ---------------- NCHW fp32 -> HWC f16 (octet-swizzled, key=(w+1)&7) ----------------
__global__ __launch_bounds__(256) void k_to_hwc(const float* __restrict__ in,
                                                _Float16* __restrict__ out) {
  int h = blockIdx.x, b = blockIdx.y;
  __shared__ _Float16 t[128 * 128];  // [c-chunk][w]
  for (int cc = 0; cc < 4; cc++) {
    int c0 = cc * 128;
    __syncthreads();
    for (int i = 0; i < 16; i++) {
      int linear = i * 256 + threadIdx.x;  // 4096 float4 loads
      int c = linear >> 5, w4 = linear & 31;
      float4 v = *reinterpret_cast<const float4*>(
          in + ((size_t)(b * 512 + c0 + c) * IMH + h) * IMW + w4 * 4);
      _Float16* d = t + c * 128 + w4 * 4;
      d[0] = (_Float16)v.x; d[1] = (_Float16)v.y;
      d[2] = (_Float16)v.z; d[3] = (_Float16)v.w;
    }
    __syncthreads();
    for (int i = 0; i < 8; i++) {
      int linear = i * 256 + threadIdx.x;  // 2048 tasks: (octet j, pixel w)
      int j = linear >> 7, w = linear & 127;
      _Float16 v[8];
#pragma unroll
      for (int u = 0; u < 8; u++) v[u] = t[(j * 8 + u) * 128 + w];
      int c = c0 + j * 8;
      int key = (w + 1) & 7;
      int cs = (c & ~63) | (((((c >> 3) & 7) ^ key) & 7) << 3);
      *reinterpret_cast<f16x8*>(out + (((size_t)(b * IMH + h) * IMW + w) * 512) + cs) =
          *reinterpret_cast<const f16x8*>(v);
    }
  }
}

// ---------------- conv weights [o][c][3][3] fp32 -> [kk][o][c_swz] f16 (key=o&7) ----------------
__global__ __launch_bounds__(256) void k_wxform(const float* __restrict__ w,
                                                _Float16* __restrict__ o_, int Cout, int Cin,
                                                int total) {
  int idx = blockIdx.x * 256 + threadIdx.x;
  if (idx >= total) return;
  int c = idx % Cin;
  int t2 = idx / Cin;
  int oc = t2 % Cout;
  int kk = t2 / Cout;
  int ky = kk / 3, kx = kk % 3;
  float v = w[(((size_t)oc * Cin + c) * 3 + ky) * 3 + kx];
  int key = oc & 7;
  int cs = (c & ~63) | (((((c >> 3) & 7) ^ key) & 7) << 3) | (c & 7);
  o_[((size_t)kk * Cout + oc) * Cin + cs] = (_Float16)v;
}

// ---------------- 1x1 weights [o][c] fp32 -> [o][c_swz] f16 (key=o&7), 512x512 ----------------
__global__ __launch_bounds__(256) void k_wxform1x1(const float* __restrict__ w,
                                                   _Float16* __restrict__ o_) {
  int idx = blockIdx.x * 256 + threadIdx.x;  // 262144 total
  int c = idx & 511;
  int oc = idx >> 9;
  int key = oc & 7;
  int cs = (c & ~63) | (((((c >> 3) & 7) ^ key) & 7) << 3) | (c & 7);
  o_[((size_t)oc << 9) + cs] = (_Float16)w[idx];
}

// ---------------- MFMA 1x1 conv (512x512 GEMM over pixels) ----------------
// Same fragment scheme as k_conv_mfma, no taps/halo. B rows = pixels of one
// image row (key (r+1)&7 — matches HWC buffers written with key (w+1)&7).
__global__ __launch_bounds__(256) void k_gemm_mfma(
    const _Float16* __restrict__ xh, const _Float16* __restrict__ wT,
    const float* __restrict__ bias,
    float* __restrict__ out_f32, _Float16* __restrict__ out_hwc) {
  int mt = blockIdx.x;   // out-channel tile (0..3)
  int h = blockIdx.y;    // image row
  int b = blockIdx.z;
  __shared__ _Float16 ldsA[128 * 64];
  __shared__ _Float16 ldsB[128 * 64];
  int tid = threadIdx.x;
  int wave = tid >> 6, lane = tid & 63;
  int wr = wave >> 1, wc = wave & 1;
  int l15 = lane & 15, l4 = lane >> 4;
  f32x4 acc[4][4] = {};
  for (int ci = 0; ci < 8; ci++) {
    int c0 = ci << 6;
    for (int it = 0; it < 4; it++) {
      int q = it * 4 + wave;
      gload16(xh + (((size_t)(b * IMH + h) * IMW) + q * 8 + (lane >> 3)) * 512 +
                  c0 + (lane & 7) * 8,
              ldsB + q * 512);
      gload16(wT + ((size_t)(mt * 128 + q * 8 + (lane >> 3))) * 512 + c0 + (lane & 7) * 8,
              ldsA + q * 512);
    }
    __syncthreads();
#pragma unroll
    for (int ks = 0; ks < 2; ks++) {
      f16x8 af[4], bf[4];
#pragma unroll
      for (int m = 0; m < 4; m++) {
        int o = wr * 64 + m * 16 + l15;
        int oct = (ks * 4 + l4) ^ (o & 7);
        af[m] = *reinterpret_cast<const f16x8*>(ldsA + o * 64 + oct * 8);
      }
#pragma unroll
      for (int n = 0; n < 4; n++) {
        int r = wc * 64 + n * 16 + l15;
        int oct = (ks * 4 + l4) ^ ((r + 1) & 7);
        bf[n] = *reinterpret_cast<const f16x8*>(ldsB + r * 64 + oct * 8);
      }
#pragma unroll
      for (int m = 0; m < 4; m++)
#pragma unroll
        for (int n = 0; n < 4; n++)
          acc[m][n] = __builtin_amdgcn_mfma_f32_16x16x32_f16(af[m], bf[n],
                                                             acc[m][n], 0, 0, 0);
    }
    __syncthreads();
  }
#pragma unroll
  for (int m = 0; m < 4; m++) {
#pragma unroll
    for (int n = 0; n < 4; n++) {
      f32x4 v = acc[m][n];
      int px = wc * 64 + n * 16 + l15;
      int obase = mt * 128 + wr * 64 + m * 16 + l4 * 4;
      if (out_hwc) {
        _Float16 hv[4];
#pragma unroll
        for (int r = 0; r < 4; r++) hv[r] = (_Float16)(v[r] + bias[obase + r]);
        int key = (px + 1) & 7;
        int cs = (obase & ~63) | (((((obase >> 3) & 7) ^ key) & 7) << 3) | (obase & 7);
        *reinterpret_cast<uint2*>(out_hwc + ((size_t)(b * IMH + h) * IMW + px) * 512 + cs) =
            *reinterpret_cast<const uint2*>(hv);
      } else {
#pragma unroll
        for (int r = 0; r < 4; r++) {
          int o = obase + r;
          out_f32[((size_t)(b * 512 + o)) * HW + h * IMW + px] = v[r] + bias[o];
        }
      }
    }
  }
}

// ---------------- MFMA 3x3 conv + BN + ReLU ----------------
__global__ __launch_bounds__(256) void k_conv_mfma(
    const _Float16* __restrict__ srcA, const _Float16* __restrict__ srcB,
    int CA, int CB,
    const _Float16* __restrict__ wT,
    const float* __restrict__ bn_g, const float* __restrict__ bn_b,
    const float* __restrict__ bn_m, const float* __restrict__ bn_v,
    float* __restrict__ out_f32, _Float16* __restrict__ out_hwc) {
  int mt = blockIdx.x;   // out-channel tile (0..3)
  int h = blockIdx.y;    // output row
  int b = blockIdx.z;
  int Cin = CA + CB;
  __shared__ _Float16 ldsA[128 * 64];  // [o][c] octet-swizzled (key o&7)
  __shared__ _Float16 ldsB[130 * 64];  // [w+1][c] octet-swizzled (key (w+1)&7), rows 0/129 = halo
  int tid = threadIdx.x;
  int wave = tid >> 6, lane = tid & 63;
  int wr = wave >> 1, wc = wave & 1;
  int l15 = lane & 15, l4 = lane >> 4;
  f32x4 acc[4][4] = {};
  // zero halo rows once (never overwritten by staging)
  if (tid < 32) ((float*)ldsB)[tid] = 0.f;
  else if (tid < 64) ((float*)ldsB)[129 * 32 + (tid - 32)] = 0.f;

  const int nc = Cin >> 6;
  for (int ky = 0; ky < 3; ky++) {
    int hh = h + ky - 1;
    if (hh < 0 || hh > 127) continue;
    for (int ci = 0; ci < nc; ci++) {
      int c0 = ci << 6;
      const _Float16* src;
      int cc0, Cbuf;
      if (c0 < CA) { src = srcA; cc0 = c0; Cbuf = CA; }
      else { src = srcB; cc0 = c0 - CA; Cbuf = CB; }
      for (int it = 0; it < 4; it++) {
        int q = it * 4 + wave;
        gload16(src + (((size_t)(b * IMH + hh) * IMW + q * 8 + (lane >> 3)) * Cbuf +
                       cc0 + (lane & 7) * 8),
                ldsB + 64 + q * 512);
      }
      for (int kx = 0; kx < 3; kx++) {
        const _Float16* wbase =
            wT + ((size_t)((ky * 3 + kx) * 512 + mt * 128)) * Cin + c0;
        for (int it = 0; it < 4; it++) {
          int q = it * 4 + wave;
          gload16(wbase + (size_t)(q * 8 + (lane >> 3)) * Cin + (lane & 7) * 8,
                  ldsA + q * 512);
        }
        __syncthreads();
#pragma unroll
        for (int ks = 0; ks < 2; ks++) {
          f16x8 af[4], bf[4];
#pragma unroll
          for (int m = 0; m < 4; m++) {
            int o = wr * 64 + m * 16 + l15;
            int oct = (ks * 4 + l4) ^ (o & 7);
            af[m] = *reinterpret_cast<const f16x8*>(ldsA + o * 64 + oct * 8);
          }
#pragma unroll
          for (int n = 0; n < 4; n++) {
            int r = wc * 64 + n * 16 + l15 + kx;
            int oct = (ks * 4 + l4) ^ (r & 7);
            bf[n] = *reinterpret_cast<const f16x8*>(ldsB + r * 64 + oct * 8);
          }
#pragma unroll
          for (int m = 0; m < 4; m++)
#pragma unroll
            for (int n = 0; n < 4; n++)
              acc[m][n] = __builtin_amdgcn_mfma_f32_16x16x32_f16(af[m], bf[n],
                                                                 acc[m][n], 0, 0, 0);
        }
        __syncthreads();
      }
    }
  }
#pragma unroll
  for (int m = 0; m < 4; m++) {
#pragma unroll
    for (int n = 0; n < 4; n++) {
      f32x4 v = acc[m][n];
      int px = wc * 64 + n * 16 + l15;
      int obase = mt * 128 + wr * 64 + m * 16 + l4 * 4;
      if (out_hwc) {
        _Float16 hv[4];
#pragma unroll
        for (int r = 0; r < 4; r++) {
          int o = obase + r;
          float sc = bn_g[o] * rsqrtf(bn_v[o] + 1e-5f);
          float sh = bn_b[o] - bn_m[o] * sc;
          hv[r] = (_Float16)fmaxf(v[r] * sc + sh, 0.f);
        }
        int key = (px + 1) & 7;
        int cs = (obase & ~63) | (((((obase >> 3) & 7) ^ key) & 7) << 3) | (obase & 7);
        *reinterpret_cast<uint2*>(out_hwc + ((size_t)(b * IMH + h) * IMW + px) * 512 + cs) =
            *reinterpret_cast<const uint2*>(hv);
      } else {
#pragma unroll
        for (int r = 0; r < 4; r++) {
          int o = obase + r;
          float sc = bn_g[o] * rsqrtf(bn_v[o] + 1e-5f);
          float sh = bn_b[o] - bn_m[o] * sc;
          out_f32[((size_t)(b * 512 + o)) * HW + h * IMW + px] =
              fmaxf(v[r] * sc + sh, 0.f);
        }
      }
    }
  }
}

extern "C" void kernel_launch(void* const* d_in, const int* in_sizes, int n_in,
                              void* d_out, int out_size, void* d_ws, size_t ws_size,
                              hipStream_t stream) {
  const float* x = (const float*)d_in[0];
  const float* gc = (const float*)d_in[1];
  const float* fd_w = (const float*)d_in[2];
  const float* fd_b = (const float*)d_in[3];
  const float* off_w = (const float*)d_in[4];
  const float* off_b = (const float*)d_in[5];
  const float* scale_w = (const float*)d_in[6];
  const float* scale_b = (const float*)d_in[7];
  const float* angle_w = (const float*)d_in[8];
  const float* angle_b = (const float*)d_in[9];
  const float* q_w = (const float*)d_in[10];
  const float* q_b = (const float*)d_in[11];
  const float* k_w = (const float*)d_in[12];
  const float* k_b = (const float*)d_in[13];
  const float* v_w = (const float*)d_in[14];
  const float* v_b = (const float*)d_in[15];
  const float* proj_w = (const float*)d_in[16];
  const float* proj_b = (const float*)d_in[17];
  const float* conv1_w = (const float*)d_in[18];
  const float* bn1_g = (const float*)d_in[19];
  const float* bn1_b = (const float*)d_in[20];
  const float* bn1_m = (const float*)d_in[21];
  const float* bn1_v = (const float*)d_in[22];
  const float* conv2_w = (const float*)d_in[23];
  const float* bn2_g = (const float*)d_in[24];
  const float* bn2_b = (const float*)d_in[25];
  const float* bn2_m = (const float*)d_in[26];
  const float* bn2_v = (const float*)d_in[27];

  // Workspace: identical 243.5 MB footprint to the passing round-3 layout.
  float* ws = (float*)d_ws;
  float* f_probs = ws; ws += 1048576;   // (B,32,HW)
  float* f_grid = ws; ws += 524288;     // (16,HW,2)
  float* f_pooled = ws; ws += 16384;
  float* f_off = ws; ws += 512;
  float* f_scl = ws; ws += 512;
  float* f_ang = ws; ws += 256;
  float* f_lc = ws; ws += 524288;       // wTq+wTk early; lc after k_lc
  float* f_v2 = ws; ws += 32768;        // (2,32,512)
  float* f_tp = ws; ws += 8388608;      // tp fp32; later x_hwc (f16, exact fit)
  float* f_A = ws; ws += 16777216;      // key_feat fp32; later h1_hwc (f16)
  float* f_B = ws; ws += 16777216;      // Yq fp32; later ctx_hwc + wT1/wT2/wTp
  float* f_C = ws; ws += 16777216;      // xh_early (f16, lower half); later tx fp32

  _Float16* xh_early = (_Float16*)f_C;                    // 16.7M f16 (lower half of f_C)
  _Float16* wTq = (_Float16*)f_lc;                        // 262144 f16
  _Float16* wTk = (_Float16*)(f_lc + 131072);             // 262144 f16
  _Float16* x_hwc = (_Float16*)f_tp;                      // built after k_lc
  _Float16* h1_hwc = (_Float16*)f_A;
  _Float16* ctx_hwc = (_Float16*)f_B;                     // lower half
  _Float16* wT1 = (_Float16*)(f_B + 8388608);             // 9*512*1024 f16
  _Float16* wT2 = (_Float16*)(f_B + 8388608 + 2359296);   // 9*512*512 f16
  _Float16* wTp = (_Float16*)(f_B + 8388608 + 2359296 + 1179648);  // 512*512 f16
  _Float16* att_hwc = (_Float16*)d_out;                   // scratch; conv2 overwrites

  // early transforms for q/k MFMA gemms
  k_to_hwc<<<dim3(128, 2), 256, 0, stream>>>(x, xh_early);
  k_wxform1x1<<<dim3(1024), 256, 0, stream>>>(q_w, wTq);
  k_wxform1x1<<<dim3(1024), 256, 0, stream>>>(k_w, wTk);

  k_logits<<<dim3(64, 2), 256, 0, stream>>>(x, fd_w, fd_b, f_probs);
  k_softmax_sp<<<dim3(64), 256, 0, stream>>>(f_probs);
  k_pool<<<dim3(4, 4, 2), 256, 0, stream>>>(x, f_pooled);
  k_heads<<<dim3(4, 4, 2), 256, 0, stream>>>(f_pooled, off_w, off_b, scale_w, scale_b,
                                             angle_w, angle_b, f_off, f_scl, f_ang);
  k_grid<<<dim3(64, 16), 256, 0, stream>>>(f_off, f_scl, f_ang, f_grid);

  // key_feat & Yq via MFMA (f16 in, fp32 NCHW out)
  k_gemm_mfma<<<dim3(4, 128, 2), 256, 0, stream>>>(xh_early, wTk, k_b, f_A, nullptr);
  k_gemm_mfma<<<dim3(4, 128, 2), 256, 0, stream>>>(xh_early, wTq, q_b, f_B, nullptr);

  // sampling (tx clobbers xh_early — dead after the gemms)
  k_gsample<<<dim3(64, 16), 256, 0, stream>>>(f_A, 64, 16, f_grid, f_C);
  k_gsample<<<dim3(64, 16), 256, 0, stream>>>(f_probs, 32, 2, f_grid, f_tp);
  k_lc<<<dim3(256), 256, 0, stream>>>(f_C, f_tp, f_lc);   // clobbers wTq/wTk (dead)
  // rebuild x_hwc for conv1 (tp dead)
  k_to_hwc<<<dim3(128, 2), 256, 0, stream>>>(x, x_hwc);
  k_v2<<<dim3(64), 256, 0, stream>>>(gc, v_w, v_b, f_v2);
  k_attn<<<dim3(8, 16, 2), 256, 0, stream>>>(f_B, f_lc, f_v2, att_hwc);
  // Yq dead -> conv/proj weight transforms into f_B upper half
  k_wxform1x1<<<dim3(1024), 256, 0, stream>>>(proj_w, wTp);
  k_wxform<<<dim3(18432), 256, 0, stream>>>(conv1_w, wT1, 512, 1024, 9 * 512 * 1024);
  k_wxform<<<dim3(9216), 256, 0, stream>>>(conv2_w, wT2, 512, 512, 9 * 512 * 512);
  // ctx = proj(att) via MFMA, emitted directly as swizzled HWC f16
  k_gemm_mfma<<<dim3(4, 128, 2), 256, 0, stream>>>(att_hwc, wTp, proj_b, nullptr, ctx_hwc);
  // conv1: concat(x, ctx) -> h1 (HWC f16)
  k_conv_mfma<<<dim3(4, 128, 2), 256, 0, stream>>>(x_hwc, ctx_hwc, 512, 512, wT1,
                                                   bn1_g, bn1_b, bn1_m, bn1_v,
                                                   nullptr, h1_hwc);
  // conv2: h1 -> d_out (NCHW fp32)
  k_conv_mfma<<<dim3(4, 128, 2), 256, 0, stream>>>(h1_hwc, h1_hwc, 512, 0, wT2,
                                                   bn2_g, bn2_b, bn2_m, bn2_v,
                                                   (float*)d_out, nullptr);
}

// Round 5
// 1299.318 us; speedup vs baseline: 7.6881x; 1.1471x over previous
//
#include <hip/hip_runtime.h>
#include <hip/hip_bf16.h>
#include <math.h>

#define HW 16384
#define IMH 128
#define IMW 128

typedef _Float16 f16x8 __attribute__((ext_vector_type(8)));
typedef float f32x4 __attribute__((ext_vector_type(4)));

__device__ __forceinline__ void gload16(const void* g, void* l) {
  __builtin_amdgcn_global_load_lds(
      (const __attribute__((address_space(1))) void*)g,
      (__attribute__((address_space(3))) void*)l, 16, 0, 0);
}

// ---------------- logits = fd_w @ x + fd_b ----------------
__global__ __launch_bounds__(256) void k_logits(const float* __restrict__ x,
                                                const float* __restrict__ fd_w,
                                                const float* __restrict__ fd_b,
                                                float* __restrict__ probs) {
  __shared__ float w[256 * 32];
  int b = blockIdx.y;
  int pix = blockIdx.x * 256 + threadIdx.x;
  float acc[32];
#pragma unroll
  for (int k = 0; k < 32; k++) acc[k] = fd_b[k];
  const float* xp = x + (size_t)b * 512 * HW + pix;
  for (int half = 0; half < 2; half++) {
    int cbase = half * 256;
    __syncthreads();
    for (int i = threadIdx.x; i < 256 * 32; i += 256) {
      int c = i >> 5, k = i & 31;
      w[i] = fd_w[k * 512 + cbase + c];
    }
    __syncthreads();
    for (int c = 0; c < 256; c++) {
      float xv = xp[(size_t)(cbase + c) * HW];
#pragma unroll
      for (int k = 0; k < 32; k++) acc[k] += xv * w[c * 32 + k];
    }
  }
#pragma unroll
  for (int k = 0; k < 32; k++) probs[((size_t)(b * 32 + k)) * HW + pix] = acc[k];
}

// ---------------- softmax over spatial (16384) per (b,k) ----------------
__global__ __launch_bounds__(256) void k_softmax_sp(float* __restrict__ probs) {
  int row = blockIdx.x;
  float* p = probs + (size_t)row * HW;
  __shared__ float red[256];
  float mx = -1e30f;
  for (int i = threadIdx.x; i < HW; i += 256) mx = fmaxf(mx, p[i]);
  red[threadIdx.x] = mx;
  __syncthreads();
  for (int s = 128; s > 0; s >>= 1) {
    if (threadIdx.x < s) red[threadIdx.x] = fmaxf(red[threadIdx.x], red[threadIdx.x + s]);
    __syncthreads();
  }
  mx = red[0];
  __syncthreads();
  float sum = 0.f;
  for (int i = threadIdx.x; i < HW; i += 256) sum += expf(p[i] - mx);
  red[threadIdx.x] = sum;
  __syncthreads();
  for (int s = 128; s > 0; s >>= 1) {
    if (threadIdx.x < s) red[threadIdx.x] += red[threadIdx.x + s];
    __syncthreads();
  }
  float inv = 1.0f / red[0];
  for (int i = threadIdx.x; i < HW; i += 256) p[i] = expf(p[i] - mx) * inv;
}

// ---------------- probs (B,32,HW) -> probsT (B,HW,32) ----------------
__global__ __launch_bounds__(256) void k_probs_t(const float* __restrict__ pr,
                                                 float* __restrict__ out) {
  int blk = blockIdx.x, b = blockIdx.y;
  __shared__ float t[32][257];
  int tid = threadIdx.x;
  int px0 = blk * 256;
  for (int i = 0; i < 32; i++)
    t[i][tid] = pr[((size_t)(b * 32 + i)) * HW + px0 + tid];
  __syncthreads();
  float* op = out + ((size_t)b * HW + px0 + tid) * 32;
#pragma unroll
  for (int k = 0; k < 32; k++) op[k] = t[k][tid];
}

// ---------------- pooled = leaky(mean 32x32 window) ----------------
__global__ __launch_bounds__(256) void k_pool(const float* __restrict__ x,
                                              float* __restrict__ pooled) {
  int b = blockIdx.z, ih = blockIdx.y, iw = blockIdx.x;
  for (int c = threadIdx.x; c < 512; c += 256) {
    const float* xp = x + ((size_t)(b * 512 + c) * IMH + ih * 32) * IMW + iw * 32;
    float s = 0.f;
    for (int r = 0; r < 32; r++)
      for (int cc = 0; cc < 32; cc++) s += xp[r * IMW + cc];
    s *= (1.0f / 1024.0f);
    if (s < 0.f) s *= 0.01f;
    pooled[(b * 512 + c) * 16 + ih * 4 + iw] = s;
  }
}

// ---------------- off / scl / ang heads ----------------
__global__ __launch_bounds__(256) void k_heads(const float* __restrict__ pooled,
                                               const float* __restrict__ off_w, const float* __restrict__ off_b,
                                               const float* __restrict__ scale_w, const float* __restrict__ scale_b,
                                               const float* __restrict__ angle_w, const float* __restrict__ angle_b,
                                               float* __restrict__ f_off, float* __restrict__ f_scl,
                                               float* __restrict__ f_ang) {
  int b = blockIdx.z, ih = blockIdx.y, iw = blockIdx.x;
  __shared__ float pl[512];
  int ij = ih * 4 + iw;
  for (int c = threadIdx.x; c < 512; c += 256) pl[c] = pooled[(b * 512 + c) * 16 + ij];
  __syncthreads();
  int t = threadIdx.x;
  if (t < 40) {
    const float* wt;
    float bias;
    if (t < 16) { wt = off_w + t * 512; bias = off_b[t]; }
    else if (t < 32) { int u = t - 16; wt = scale_w + u * 512; bias = scale_b[u]; }
    else { int u = t - 32; wt = angle_w + u * 512; bias = angle_b[u]; }
    float s = bias;
    for (int c = 0; c < 512; c++) s += pl[c] * wt[c];
    if (t < 16) {
      int n = t / 2, l = t % 2;
      f_off[((b * 8 + n) * 2 + l) * 16 + ij] = s * (1.0f / 32.0f);
    } else if (t < 32) {
      int u = t - 16;
      int n = u / 2, l = u % 2;
      f_scl[((b * 8 + n) * 2 + l) * 16 + ij] = s;
    } else {
      int n = t - 32;
      f_ang[(b * 8 + n) * 16 + ij] = s;
    }
  }
}

// ---------------- sampling grid ----------------
__global__ __launch_bounds__(256) void k_grid(const float* __restrict__ f_off,
                                              const float* __restrict__ f_scl,
                                              const float* __restrict__ f_ang,
                                              float* __restrict__ grid) {
  int p = blockIdx.y;
  int hw = blockIdx.x * 256 + threadIdx.x;
  int h = hw >> 7, w = hw & 127;
  int ih = h >> 5, r = h & 31, iw = w >> 5, cs = w & 31;
  int ij = ih * 4 + iw;
  float off0 = f_off[(p * 2 + 0) * 16 + ij], off1 = f_off[(p * 2 + 1) * 16 + ij];
  float scl0 = f_scl[(p * 2 + 0) * 16 + ij], scl1 = f_scl[(p * 2 + 1) * 16 + ij];
  float a = f_ang[p * 16 + ij];
  float sa = sinf(a), ca = cosf(a);
  float bwv = ((float)cs - 15.5f) * (2.0f / 127.0f);
  float bhv = ((float)r - 15.5f) * (2.0f / 127.0f);
  float wc0 = bwv * (scl0 + 1.0f);
  float wc1 = bhv * (scl1 + 1.0f);
  float wrw = -1.0f + 2.0f * ((float)(iw * 32) + 15.5f) / 127.0f;
  float wrh = -1.0f + 2.0f * ((float)(ih * 32) + 15.5f) / 127.0f;
  float c0 = wrw + (-wc1 * sa + wc0 * ca) + off0;
  float c1 = wrh + (wc1 * ca + wc0 * sa) + off1;
  size_t o = ((size_t)p * HW + hw) * 2;
  grid[o] = c0;
  grid[o + 1] = c1;
}

// ---------------- fused grid-sample(key,probs) + lc contraction ----------------
// Block = (p, win). lc[p*16+win][k][d] = sum_s tp[s][k] * tx[s][d], with
// tx/tp gathered bilinearly from kf (HWC f16, head slice p&7 of batch p>>3)
// and probsT (HWK f32, batch p&1). No tx/tp materialization in DRAM.
__global__ __launch_bounds__(256) void k_samplc(const _Float16* __restrict__ kf,
                                                const float* __restrict__ probsT,
                                                const float* __restrict__ grid,
                                                float* __restrict__ lc) {
  int idx2 = blockIdx.x;
  int p = idx2 >> 4, win = idx2 & 15;
  int ih = win >> 2, iw = win & 3;
  int bk = p >> 3, n = p & 7, bp = p & 1;
  __shared__ int s_off[128][4];
  __shared__ float s_w[128][4];
  __shared__ float s_tx[128][65];
  __shared__ float s_tp[128][33];
  int tid = threadIdx.x;
  int k = tid >> 3, dg = tid & 7;
  float acc[8] = {};
  const _Float16* kfb = kf + (size_t)bk * HW * 512 + n * 64;
  const float* prb = probsT + (size_t)bp * HW * 32;
  for (int c0 = 0; c0 < 1024; c0 += 128) {
    // phase 1: taps + weights for this chunk's 128 samples
    if (tid < 128) {
      int s = c0 + tid;
      int pix = (ih * 32 + (s >> 5)) * IMW + iw * 32 + (s & 31);
      float gx = grid[((size_t)p * HW + pix) * 2 + 0];
      float gy = grid[((size_t)p * HW + pix) * 2 + 1];
      gx = (gx + 1.0f) * 0.5f * 127.0f;
      gy = (gy + 1.0f) * 0.5f * 127.0f;
      float x0f = floorf(gx), y0f = floorf(gy);
      float wx1 = gx - x0f, wx0 = 1.0f - wx1;
      float wy1 = gy - y0f, wy0 = 1.0f - wy1;
      int x0 = (int)x0f, y0 = (int)y0f;
      bool vx0 = (x0f >= 0.f) && (x0f <= 127.f);
      bool vx1 = (x0f + 1.0f >= 0.f) && (x0f + 1.0f <= 127.f);
      bool vy0 = (y0f >= 0.f) && (y0f <= 127.f);
      bool vy1 = (y0f + 1.0f >= 0.f) && (y0f + 1.0f <= 127.f);
      int x0c = min(max(x0, 0), 127), x1c = min(max(x0 + 1, 0), 127);
      int y0c = min(max(y0, 0), 127), y1c = min(max(y0 + 1, 0), 127);
      s_off[tid][0] = y0c * IMW + x0c;
      s_off[tid][1] = y0c * IMW + x1c;
      s_off[tid][2] = y1c * IMW + x0c;
      s_off[tid][3] = y1c * IMW + x1c;
      s_w[tid][0] = wx0 * wy0 * ((vx0 && vy0) ? 1.f : 0.f);
      s_w[tid][1] = wx1 * wy0 * ((vx1 && vy0) ? 1.f : 0.f);
      s_w[tid][2] = wx0 * wy1 * ((vx0 && vy1) ? 1.f : 0.f);
      s_w[tid][3] = wx1 * wy1 * ((vx1 && vy1) ? 1.f : 0.f);
    }
    __syncthreads();
    // phase 2a: gather tx (128 samples x 64 d): task = (sl, d-octet)
#pragma unroll
    for (int i = 0; i < 4; i++) {
      int task = tid + i * 256;
      int sl = task >> 3, d8 = (task & 7) * 8;
      float vv[8] = {};
#pragma unroll
      for (int t = 0; t < 4; t++) {
        float wt = s_w[sl][t];
        f16x8 kv = *reinterpret_cast<const f16x8*>(kfb + (size_t)s_off[sl][t] * 512 + d8);
#pragma unroll
        for (int j = 0; j < 8; j++) vv[j] += wt * (float)kv[j];
      }
#pragma unroll
      for (int j = 0; j < 8; j++) s_tx[sl][d8 + j] = vv[j];
    }
    // phase 2b: gather tp (128 samples x 32 k): task = (sl, k-octet)
#pragma unroll
    for (int i = 0; i < 2; i++) {
      int task = tid + i * 256;
      int sl = task >> 2, k8 = (task & 3) * 8;
      float vv[8] = {};
#pragma unroll
      for (int t = 0; t < 4; t++) {
        float wt = s_w[sl][t];
        const float* pp = prb + (size_t)s_off[sl][t] * 32 + k8;
#pragma unroll
        for (int j = 0; j < 8; j++) vv[j] += wt * pp[j];
      }
#pragma unroll
      for (int j = 0; j < 8; j++) s_tp[sl][k8 + j] = vv[j];
    }
    __syncthreads();
    // phase 3: MAC
    for (int sl = 0; sl < 128; sl++) {
      float tv = s_tp[sl][k];
      const float* xr = &s_tx[sl][dg * 8];
#pragma unroll
      for (int j = 0; j < 8; j++) acc[j] += tv * xr[j];
    }
    __syncthreads();
  }
  float* lp = lc + ((size_t)idx2 * 32 + k) * 64 + dg * 8;
#pragma unroll
  for (int j = 0; j < 8; j++) lp[j] = acc[j];
}

// ---------------- v2[j][k][o] = gc[j][k]·v_w[o] + v_b[o] ----------------
__global__ __launch_bounds__(256) void k_v2(const float* __restrict__ gc,
                                            const float* __restrict__ v_w,
                                            const float* __restrict__ v_b,
                                            float* __restrict__ v2) {
  int j = blockIdx.x >> 5, k = blockIdx.x & 31;
  __shared__ float g[512];
  for (int c = threadIdx.x; c < 512; c += 256) g[c] = gc[((size_t)j * 32 + k) * 512 + c];
  __syncthreads();
  for (int o = threadIdx.x; o < 512; o += 256) {
    float s = v_b[o];
    const float* wp = v_w + (size_t)o * 512;
    for (int c = 0; c < 512; c++) s += g[c] * wp[c];
    v2[((size_t)j * 32 + k) * 512 + o] = s;
  }
}

// ---------------- attention per (b, win, n); q from HWC f16; att -> HWC f16 swz ----------------
__global__ __launch_bounds__(256) void k_attn(const _Float16* __restrict__ yq,
                                              const float* __restrict__ lc,
                                              const float* __restrict__ v2,
                                              _Float16* __restrict__ att) {
  int n = blockIdx.x, win = blockIdx.y, b = blockIdx.z;
  int ih = win >> 2, iw = win & 3;
  __shared__ float llc[32 * 64];
  __shared__ float lv[32 * 64];
  int bnw = b * 16 + win;
  const float* lcp = lc + (size_t)(bnw * 8 + n) * 2048;
  const float* vp = v2 + (size_t)(bnw & 1) * 32 * 512 + n * 64;
  for (int i = threadIdx.x; i < 2048; i += 256) {
    llc[i] = lcp[i];
    int k = i >> 6, d = i & 63;
    lv[i] = vp[(size_t)k * 512 + d];
  }
  __syncthreads();
  const float scale = 0.125f;
  for (int rep = 0; rep < 4; rep++) {
    int s = threadIdx.x + rep * 256;
    int w = iw * 32 + (s & 31);
    int pix = (ih * 32 + (s >> 5)) * IMW + w;
    const _Float16* qp = yq + ((size_t)(b * HW) + pix) * 512 + n * 64;
    float q[64];
#pragma unroll
    for (int u = 0; u < 8; u++) {
      f16x8 v = *reinterpret_cast<const f16x8*>(qp + u * 8);
#pragma unroll
      for (int j = 0; j < 8; j++) q[u * 8 + j] = (float)v[j];
    }
    float dots[32];
#pragma unroll
    for (int k = 0; k < 32; k++) {
      float s2 = 0.f;
#pragma unroll
      for (int d = 0; d < 64; d++) s2 += q[d] * llc[k * 64 + d];
      dots[k] = s2 * scale;
    }
    float mx = -1e30f;
#pragma unroll
    for (int k = 0; k < 32; k++) mx = fmaxf(mx, dots[k]);
    float sum = 0.f;
#pragma unroll
    for (int k = 0; k < 32; k++) {
      dots[k] = expf(dots[k] - mx);
      sum += dots[k];
    }
    float inv = 1.0f / sum;
    float outv[64];
#pragma unroll
    for (int d = 0; d < 64; d++) outv[d] = 0.f;
#pragma unroll
    for (int k = 0; k < 32; k++) {
      float a = dots[k] * inv;
#pragma unroll
      for (int d = 0; d < 64; d++) outv[d] += a * lv[k * 64 + d];
    }
    int key = (w + 1) & 7;
    _Float16* ob = att + ((size_t)(b * HW) + pix) * 512 + n * 64;
#pragma unroll
    for (int u = 0; u < 8; u++) {
      _Float16 hv[8];
#pragma unroll
      for (int j = 0; j < 8; j++) hv[j] = (_Float16)outv[u * 8 + j];
      *reinterpret_cast<f16x8*>(ob + ((u ^ key) << 3)) = *reinterpret_cast<const f16x8*>(hv);
    }
  }
}

// ---------------- NCHW fp32 -> HWC f16 (octet-swizzled, key=(w+1)&7) ----------------
__global__ __launch_bounds__(256) void k_to_hwc(const float* __restrict__ in,
                                                _Float16* __restrict__ out) {
  int h = blockIdx.x, b = blockIdx.y;
  __shared__ _Float16 t[128 * 128];
  for (int cc = 0; cc < 4; cc++) {
    int c0 = cc * 128;
    __syncthreads();
    for (int i = 0; i < 16; i++) {
      int linear = i * 256 + threadIdx.x;
      int c = linear >> 5, w4 = linear & 31;
      float4 v = *reinterpret_cast<const float4*>(
          in + ((size_t)(b * 512 + c0 + c) * IMH + h) * IMW + w4 * 4);
      _Float16* d = t + c * 128 + w4 * 4;
      d[0] = (_Float16)v.x; d[1] = (_Float16)v.y;
      d[2] = (_Float16)v.z; d[3] = (_Float16)v.w;
    }
    __syncthreads();
    for (int i = 0; i < 8; i++) {
      int linear = i * 256 + threadIdx.x;
      int j = linear >> 7, w = linear & 127;
      _Float16 v[8];
#pragma unroll
      for (int u = 0; u < 8; u++) v[u] = t[(j * 8 + u) * 128 + w];
      int c = c0 + j * 8;
      int key = (w + 1) & 7;
      int cs = (c & ~63) | (((((c >> 3) & 7) ^ key) & 7) << 3);
      *reinterpret_cast<f16x8*>(out + (((size_t)(b * IMH + h) * IMW + w) * 512) + cs) =
          *reinterpret_cast<const f16x8*>(v);
    }
  }
}

// ---------------- conv weights [o][c][3][3] fp32 -> [kk][o][c_swz] f16 (key=o&7) ----------------
__global__ __launch_bounds__(256) void k_wxform(const float* __restrict__ w,
                                                _Float16* __restrict__ o_, int Cout, int Cin,
                                                int total) {
  int idx = blockIdx.x * 256 + threadIdx.x;
  if (idx >= total) return;
  int c = idx % Cin;
  int t2 = idx / Cin;
  int oc = t2 % Cout;
  int kk = t2 / Cout;
  int ky = kk / 3, kx = kk % 3;
  float v = w[(((size_t)oc * Cin + c) * 3 + ky) * 3 + kx];
  int key = oc & 7;
  int cs = (c & ~63) | (((((c >> 3) & 7) ^ key) & 7) << 3) | (c & 7);
  o_[((size_t)kk * Cout + oc) * Cin + cs] = (_Float16)v;
}

// ---------------- 1x1 weights [o][c] fp32 -> [o][c_swz] f16 (key=o&7), 512x512 ----------------
__global__ __launch_bounds__(256) void k_wxform1x1(const float* __restrict__ w,
                                                   _Float16* __restrict__ o_) {
  int idx = blockIdx.x * 256 + threadIdx.x;
  int c = idx & 511;
  int oc = idx >> 9;
  int key = oc & 7;
  int cs = (c & ~63) | (((((c >> 3) & 7) ^ key) & 7) << 3) | (c & 7);
  o_[((size_t)oc << 9) + cs] = (_Float16)w[idx];
}

// ---------------- MFMA 1x1 conv (512x512 GEMM over pixels) ----------------
__global__ __launch_bounds__(256) void k_gemm_mfma(
    const _Float16* __restrict__ xh, const _Float16* __restrict__ wT,
    const float* __restrict__ bias,
    float* __restrict__ out_f32, _Float16* __restrict__ out_hwc, int swz) {
  int mt = blockIdx.x;
  int h = blockIdx.y;
  int b = blockIdx.z;
  __shared__ _Float16 ldsA[128 * 64];
  __shared__ _Float16 ldsB[128 * 64];
  int tid = threadIdx.x;
  int wave = tid >> 6, lane = tid & 63;
  int wr = wave >> 1, wc = wave & 1;
  int l15 = lane & 15, l4 = lane >> 4;
  f32x4 acc[4][4] = {};
  for (int ci = 0; ci < 8; ci++) {
    int c0 = ci << 6;
    for (int it = 0; it < 4; it++) {
      int q = it * 4 + wave;
      gload16(xh + (((size_t)(b * IMH + h) * IMW) + q * 8 + (lane >> 3)) * 512 +
                  c0 + (lane & 7) * 8,
              ldsB + q * 512);
      gload16(wT + ((size_t)(mt * 128 + q * 8 + (lane >> 3))) * 512 + c0 + (lane & 7) * 8,
              ldsA + q * 512);
    }
    __syncthreads();
#pragma unroll
    for (int ks = 0; ks < 2; ks++) {
      f16x8 af[4], bf[4];
#pragma unroll
      for (int m = 0; m < 4; m++) {
        int o = wr * 64 + m * 16 + l15;
        int oct = (ks * 4 + l4) ^ (o & 7);
        af[m] = *reinterpret_cast<const f16x8*>(ldsA + o * 64 + oct * 8);
      }
#pragma unroll
      for (int n = 0; n < 4; n++) {
        int r = wc * 64 + n * 16 + l15;
        int oct = (ks * 4 + l4) ^ ((r + 1) & 7);
        bf[n] = *reinterpret_cast<const f16x8*>(ldsB + r * 64 + oct * 8);
      }
#pragma unroll
      for (int m = 0; m < 4; m++)
#pragma unroll
        for (int n = 0; n < 4; n++)
          acc[m][n] = __builtin_amdgcn_mfma_f32_16x16x32_f16(af[m], bf[n],
                                                             acc[m][n], 0, 0, 0);
    }
    __syncthreads();
  }
#pragma unroll
  for (int m = 0; m < 4; m++) {
#pragma unroll
    for (int n = 0; n < 4; n++) {
      f32x4 v = acc[m][n];
      int px = wc * 64 + n * 16 + l15;
      int obase = mt * 128 + wr * 64 + m * 16 + l4 * 4;
      if (out_hwc) {
        _Float16 hv[4];
#pragma unroll
        for (int r = 0; r < 4; r++) hv[r] = (_Float16)(v[r] + bias[obase + r]);
        int key = swz ? ((px + 1) & 7) : 0;
        int cs = (obase & ~63) | (((((obase >> 3) & 7) ^ key) & 7) << 3) | (obase & 7);
        *reinterpret_cast<uint2*>(out_hwc + ((size_t)(b * IMH + h) * IMW + px) * 512 + cs) =
            *reinterpret_cast<const uint2*>(hv);
      } else {
#pragma unroll
        for (int r = 0; r < 4; r++) {
          int o = obase + r;
          out_f32[((size_t)(b * 512 + o)) * HW + h * IMW + px] = v[r] + bias[o];
        }
      }
    }
  }
}

// ---------------- MFMA 3x3 conv + BN + ReLU ----------------
__global__ __launch_bounds__(256) void k_conv_mfma(
    const _Float16* __restrict__ srcA, const _Float16* __restrict__ srcB,
    int CA, int CB,
    const _Float16* __restrict__ wT,
    const float* __restrict__ bn_g, const float* __restrict__ bn_b,
    const float* __restrict__ bn_m, const float* __restrict__ bn_v,
    float* __restrict__ out_f32, _Float16* __restrict__ out_hwc) {
  int mt = blockIdx.x;
  int h = blockIdx.y;
  int b = blockIdx.z;
  int Cin = CA + CB;
  __shared__ _Float16 ldsA[128 * 64];
  __shared__ _Float16 ldsB[130 * 64];
  int tid = threadIdx.x;
  int wave = tid >> 6, lane = tid & 63;
  int wr = wave >> 1, wc = wave & 1;
  int l15 = lane & 15, l4 = lane >> 4;
  f32x4 acc[4][4] = {};
  if (tid < 32) ((float*)ldsB)[tid] = 0.f;
  else if (tid < 64) ((float*)ldsB)[129 * 32 + (tid - 32)] = 0.f;

  const int nc = Cin >> 6;
  for (int ky = 0; ky < 3; ky++) {
    int hh = h + ky - 1;
    if (hh < 0 || hh > 127) continue;
    for (int ci = 0; ci < nc; ci++) {
      int c0 = ci << 6;
      const _Float16* src;
      int cc0, Cbuf;
      if (c0 < CA) { src = srcA; cc0 = c0; Cbuf = CA; }
      else { src = srcB; cc0 = c0 - CA; Cbuf = CB; }
      for (int it = 0; it < 4; it++) {
        int q = it * 4 + wave;
        gload16(src + (((size_t)(b * IMH + hh) * IMW + q * 8 + (lane >> 3)) * Cbuf +
                       cc0 + (lane & 7) * 8),
                ldsB + 64 + q * 512);
      }
      for (int kx = 0; kx < 3; kx++) {
        const _Float16* wbase =
            wT + ((size_t)((ky * 3 + kx) * 512 + mt * 128)) * Cin + c0;
        for (int it = 0; it < 4; it++) {
          int q = it * 4 + wave;
          gload16(wbase + (size_t)(q * 8 + (lane >> 3)) * Cin + (lane & 7) * 8,
                  ldsA + q * 512);
        }
        __syncthreads();
#pragma unroll
        for (int ks = 0; ks < 2; ks++) {
          f16x8 af[4], bf[4];
#pragma unroll
          for (int m = 0; m < 4; m++) {
            int o = wr * 64 + m * 16 + l15;
            int oct = (ks * 4 + l4) ^ (o & 7);
            af[m] = *reinterpret_cast<const f16x8*>(ldsA + o * 64 + oct * 8);
          }
#pragma unroll
          for (int n = 0; n < 4; n++) {
            int r = wc * 64 + n * 16 + l15 + kx;
            int oct = (ks * 4 + l4) ^ (r & 7);
            bf[n] = *reinterpret_cast<const f16x8*>(ldsB + r * 64 + oct * 8);
          }
#pragma unroll
          for (int m = 0; m < 4; m++)
#pragma unroll
            for (int n = 0; n < 4; n++)
              acc[m][n] = __builtin_amdgcn_mfma_f32_16x16x32_f16(af[m], bf[n],
                                                                 acc[m][n], 0, 0, 0);
        }
        __syncthreads();
      }
    }
  }
#pragma unroll
  for (int m = 0; m < 4; m++) {
#pragma unroll
    for (int n = 0; n < 4; n++) {
      f32x4 v = acc[m][n];
      int px = wc * 64 + n * 16 + l15;
      int obase = mt * 128 + wr * 64 + m * 16 + l4 * 4;
      if (out_hwc) {
        _Float16 hv[4];
#pragma unroll
        for (int r = 0; r < 4; r++) {
          int o = obase + r;
          float sc = bn_g[o] * rsqrtf(bn_v[o] + 1e-5f);
          float sh = bn_b[o] - bn_m[o] * sc;
          hv[r] = (_Float16)fmaxf(v[r] * sc + sh, 0.f);
        }
        int key = (px + 1) & 7;
        int cs = (obase & ~63) | (((((obase >> 3) & 7) ^ key) & 7) << 3) | (obase & 7);
        *reinterpret_cast<uint2*>(out_hwc + ((size_t)(b * IMH + h) * IMW + px) * 512 + cs) =
            *reinterpret_cast<const uint2*>(hv);
      } else {
#pragma unroll
        for (int r = 0; r < 4; r++) {
          int o = obase + r;
          float sc = bn_g[o] * rsqrtf(bn_v[o] + 1e-5f);
          float sh = bn_b[o] - bn_m[o] * sc;
          out_f32[((size_t)(b * 512 + o)) * HW + h * IMW + px] =
              fmaxf(v[r] * sc + sh, 0.f);
        }
      }
    }
  }
}

extern "C" void kernel_launch(void* const* d_in, const int* in_sizes, int n_in,
                              void* d_out, int out_size, void* d_ws, size_t ws_size,
                              hipStream_t stream) {
  const float* x = (const float*)d_in[0];
  const float* gc = (const float*)d_in[1];
  const float* fd_w = (const float*)d_in[2];
  const float* fd_b = (const float*)d_in[3];
  const float* off_w = (const float*)d_in[4];
  const float* off_b = (const float*)d_in[5];
  const float* scale_w = (const float*)d_in[6];
  const float* scale_b = (const float*)d_in[7];
  const float* angle_w = (const float*)d_in[8];
  const float* angle_b = (const float*)d_in[9];
  const float* q_w = (const float*)d_in[10];
  const float* q_b = (const float*)d_in[11];
  const float* k_w = (const float*)d_in[12];
  const float* k_b = (const float*)d_in[13];
  const float* v_w = (const float*)d_in[14];
  const float* v_b = (const float*)d_in[15];
  const float* proj_w = (const float*)d_in[16];
  const float* proj_b = (const float*)d_in[17];
  const float* conv1_w = (const float*)d_in[18];
  const float* bn1_g = (const float*)d_in[19];
  const float* bn1_b = (const float*)d_in[20];
  const float* bn1_m = (const float*)d_in[21];
  const float* bn1_v = (const float*)d_in[22];
  const float* conv2_w = (const float*)d_in[23];
  const float* bn2_g = (const float*)d_in[24];
  const float* bn2_b = (const float*)d_in[25];
  const float* bn2_m = (const float*)d_in[26];
  const float* bn2_v = (const float*)d_in[27];

  // Workspace: identical 243.5 MB footprint to the passing round-4 layout.
  float* ws = (float*)d_ws;
  float* f_probs = ws; ws += 1048576;   // (B,32,HW)
  float* f_grid = ws; ws += 524288;     // (16,HW,2)
  float* f_pooled = ws; ws += 16384;
  float* f_off = ws; ws += 512;
  float* f_scl = ws; ws += 512;
  float* f_ang = ws; ws += 256;
  float* f_lc = ws; ws += 524288;       // wTq+wTk early; lc after samplc
  float* f_v2 = ws; ws += 32768;        // (2,32,512)
  float* f_tp = ws; ws += 8388608;      // probsT + wT1 + wT2 + wTp
  float* f_A = ws; ws += 16777216;      // kf_hwc f16; later h1_hwc f16
  float* f_B = ws; ws += 16777216;      // yq_hwc f16
  float* f_C = ws; ws += 16777216;      // xh (lower), ctx_hwc (upper)

  _Float16* wTq = (_Float16*)f_lc;                      // 262144 f16
  _Float16* wTk = (_Float16*)(f_lc + 131072);           // 262144 f16
  float* probsT = f_tp;                                 // (2,HW,32) = 1048576 f32
  _Float16* wT1 = (_Float16*)(f_tp + 1048576);          // 9*512*1024 f16
  _Float16* wT2 = (_Float16*)(f_tp + 1048576 + 2359296);// 9*512*512 f16
  _Float16* wTp = (_Float16*)(f_tp + 1048576 + 2359296 + 1179648);  // 512*512 f16
  _Float16* kf_hwc = (_Float16*)f_A;
  _Float16* h1_hwc = (_Float16*)f_A;
  _Float16* yq_hwc = (_Float16*)f_B;
  _Float16* xh = (_Float16*)f_C;
  _Float16* ctx_hwc = (_Float16*)(f_C + 8388608);
  _Float16* att_hwc = (_Float16*)d_out;

  // weight transforms + x transpose (inputs only; no deps)
  k_wxform1x1<<<dim3(1024), 256, 0, stream>>>(q_w, wTq);
  k_wxform1x1<<<dim3(1024), 256, 0, stream>>>(k_w, wTk);
  k_wxform1x1<<<dim3(1024), 256, 0, stream>>>(proj_w, wTp);
  k_wxform<<<dim3(18432), 256, 0, stream>>>(conv1_w, wT1, 512, 1024, 9 * 512 * 1024);
  k_wxform<<<dim3(9216), 256, 0, stream>>>(conv2_w, wT2, 512, 512, 9 * 512 * 512);
  k_to_hwc<<<dim3(128, 2), 256, 0, stream>>>(x, xh);

  k_logits<<<dim3(64, 2), 256, 0, stream>>>(x, fd_w, fd_b, f_probs);
  k_softmax_sp<<<dim3(64), 256, 0, stream>>>(f_probs);
  k_probs_t<<<dim3(64, 2), 256, 0, stream>>>(f_probs, probsT);
  k_pool<<<dim3(4, 4, 2), 256, 0, stream>>>(x, f_pooled);
  k_heads<<<dim3(4, 4, 2), 256, 0, stream>>>(f_pooled, off_w, off_b, scale_w, scale_b,
                                             angle_w, angle_b, f_off, f_scl, f_ang);
  k_grid<<<dim3(64, 16), 256, 0, stream>>>(f_off, f_scl, f_ang, f_grid);

  // key_feat & Yq via MFMA -> HWC f16 (unswizzled for gather/attn consumers)
  k_gemm_mfma<<<dim3(4, 128, 2), 256, 0, stream>>>(xh, wTk, k_b, nullptr, kf_hwc, 0);
  k_gemm_mfma<<<dim3(4, 128, 2), 256, 0, stream>>>(xh, wTq, q_b, nullptr, yq_hwc, 0);

  // fused grid-sample + lc (writes f_lc; wTq/wTk dead)
  k_samplc<<<dim3(256), 256, 0, stream>>>(kf_hwc, probsT, f_grid, f_lc);
  k_v2<<<dim3(64), 256, 0, stream>>>(gc, v_w, v_b, f_v2);
  k_attn<<<dim3(8, 16, 2), 256, 0, stream>>>(yq_hwc, f_lc, f_v2, att_hwc);

  // ctx = proj(att) via MFMA, emitted as swizzled HWC f16
  k_gemm_mfma<<<dim3(4, 128, 2), 256, 0, stream>>>(att_hwc, wTp, proj_b, nullptr, ctx_hwc, 1);
  // conv1: concat(x, ctx) -> h1 (HWC f16; kf dead)
  k_conv_mfma<<<dim3(4, 128, 2), 256, 0, stream>>>(xh, ctx_hwc, 512, 512, wT1,
                                                   bn1_g, bn1_b, bn1_m, bn1_v,
                                                   nullptr, h1_hwc);
  // conv2: h1 -> d_out (NCHW fp32)
  k_conv_mfma<<<dim3(4, 128, 2), 256, 0, stream>>>(h1_hwc, h1_hwc, 512, 0, wT2,
                                                   bn2_g, bn2_b, bn2_m, bn2_v,
                                                   (float*)d_out, nullptr);
}